// Round 1
// 1383.144 us; speedup vs baseline: 1.3699x; 1.3699x over previous
//
#include <hip/hip_runtime.h>
#include <math.h>

// ---------------- problem constants ----------------
#define BB     2
#define LSEG   64
#define HOP    256
#define TT     (LSEG*HOP)      // 16384
#define IN_CH  101
#define INNER  128
#define COND   81
#define LAYERS 5
#define KTAP   3
#define KH     64
#define COUT   256             // 2*INNER
#define RPL    (INNER*COUT*KTAP)   // 98304 rows per layer
#define KCH    (RPL*LAYERS)        // 491520
#define BCH    (COUT*LAYERS)       // 1280
#define NBL    (BB*LSEG)           // 128
#define XS     36                  // padded LDS row stride (f16) - bank stride 18

typedef _Float16 f16;
typedef _Float16 f16x2 __attribute__((ext_vector_type(2)));
typedef _Float16 f16x8 __attribute__((ext_vector_type(8)));
typedef float    f32x4 __attribute__((ext_vector_type(4)));

// ---------------- fc: h = fc_W @ x + fc_b -> f16 activations ----------------
__global__ __launch_bounds__(256) void k_fc(const float* __restrict__ x,
                                            const float* __restrict__ W,
                                            const float* __restrict__ bias,
                                            f16* __restrict__ out) {
    int half = blockIdx.x & 1;
    int g = (blockIdx.x >> 1)*256 + threadIdx.x;   // over BB*TT
    int b = g / TT, t = g % TT;
    float xv[IN_CH];
    const float* xp = x + (size_t)b*IN_CH*TT + t;
#pragma unroll
    for (int c = 0; c < IN_CH; ++c) xv[c] = xp[(size_t)c*TT];
    f16* op = out + (size_t)b*INNER*TT + t;
    int o0 = half*64;
    for (int o = o0; o < o0 + 64; ++o) {
        const float* wr = W + o*IN_CH;
        float a0 = bias[o], a1 = 0.f, a2 = 0.f, a3 = 0.f;
#pragma unroll
        for (int c = 0; c + 3 < IN_CH; c += 4) {
            a0 += wr[c]*xv[c]; a1 += wr[c+1]*xv[c+1];
            a2 += wr[c+2]*xv[c+2]; a3 += wr[c+3]*xv[c+3];
        }
        a0 += wr[100]*xv[100];
        op[(size_t)o*TT] = (f16)((a0+a1)+(a2+a3));
    }
}

// ---------------- predictor stage 1: h1 = lrelu(conv5(c)) ----------------
__global__ __launch_bounds__(256) void k_h1(const float* __restrict__ cc,
                                            const float* __restrict__ iW,
                                            const float* __restrict__ ib,
                                            float* __restrict__ h1buf) {
    int og = blockIdx.x & 7;
    int b  = blockIdx.x >> 3;
    __shared__ float cL[COND*LSEG];
    __shared__ float wL[8*COND*5];
    int tid = threadIdx.x;
    for (int idx = tid; idx < COND*LSEG; idx += 256)
        cL[idx] = cc[(size_t)b*COND*LSEG + idx];
    const float* wsrc = iW + (size_t)og*8*COND*5;
    for (int idx = tid; idx < 8*COND*5; idx += 256)
        wL[idx] = wsrc[idx];
    __syncthreads();
#pragma unroll
    for (int rep = 0; rep < 2; ++rep) {
        int idx = rep*256 + tid;
        int ol = idx >> 6, l = idx & 63;
        int o  = og*8 + ol;
        float acc = ib[o];
        const float* wrow = wL + ol*COND*5;
        for (int i = 0; i < COND; ++i) {
            const float* crow = cL + i*LSEG;
            const float* w5 = wrow + i*5;
#pragma unroll
            for (int k = 0; k < 5; ++k) {
                int ll = l + k - 2;
                if (ll >= 0 && ll < LSEG) acc += crow[ll]*w5[k];
            }
        }
        h1buf[((size_t)b*KH + o)*LSEG + l] = acc >= 0.f ? acc : 0.1f*acc;
    }
}

// ---------------- predictor stage 2: h2 (f32 for bias head, f16 for k_gen) ----------------
__global__ __launch_bounds__(256) void k_h2t(const float* __restrict__ h1buf,
                                             const float* __restrict__ r1W,
                                             const float* __restrict__ r1b,
                                             const float* __restrict__ r2W,
                                             const float* __restrict__ r2b,
                                             float* __restrict__ h2buf,
                                             f16* __restrict__ h2h) {
    int b = blockIdx.x;
    __shared__ float h1L[KH*LSEG];
    __shared__ float t1L[KH*LSEG];
    __shared__ float wL[KH*KH];
    int tid = threadIdx.x;
    for (int idx = tid; idx < KH*LSEG; idx += 256)
        h1L[idx] = h1buf[(size_t)b*KH*LSEG + idx];
    for (int idx = tid; idx < KH*KH; idx += 256)
        wL[idx] = r1W[idx];
    __syncthreads();
#pragma unroll
    for (int rep = 0; rep < 16; ++rep) {
        int idx = rep*256 + tid;
        int o = idx >> 6, l = idx & 63;
        float acc = r1b[o];
        const float* wr = wL + o*KH;
#pragma unroll
        for (int i = 0; i < KH; ++i) acc += wr[i]*h1L[i*LSEG + l];
        t1L[idx] = acc >= 0.f ? acc : 0.1f*acc;
    }
    __syncthreads();
    for (int idx = tid; idx < KH*KH; idx += 256)
        wL[idx] = r2W[idx];
    __syncthreads();
#pragma unroll
    for (int rep = 0; rep < 16; ++rep) {
        int idx = rep*256 + tid;
        int o = idx >> 6, l = idx & 63;
        float acc = r2b[o];
        const float* wr = wL + o*KH;
#pragma unroll
        for (int i = 0; i < KH; ++i) acc += wr[i]*t1L[i*LSEG + l];
        float h2 = h1L[o*LSEG + l] + acc;
        h2buf[((size_t)b*LSEG + l)*KH + o] = h2;           // [bl][o] f32
        h2h  [((size_t)b*LSEG + l)*KH + o] = (f16)h2;      // [bl][o] f16
    }
}

// ---------------- bias head (separate tiny kernel, once per n-block) ----------------
__global__ __launch_bounds__(256) void k_biash(const float* __restrict__ bW,
                                               const float* __restrict__ bb,
                                               const float* __restrict__ h2buf,
                                               float* __restrict__ biasbuf) {
    int tg = blockIdx.x*256 + threadIdx.x;       // 0..2559
    int b  = __builtin_amdgcn_readfirstlane(tg / BCH);
    int rb = tg % BCH;
    float w[KH];
    const float4* wp = (const float4*)(bW + (size_t)rb*KH);
#pragma unroll
    for (int q = 0; q < KH/4; ++q) {
        float4 v = wp[q];
        w[4*q] = v.x; w[4*q+1] = v.y; w[4*q+2] = v.z; w[4*q+3] = v.w;
    }
    float bv = bb[rb];
    for (int l = 0; l < LSEG; ++l) {
        const float* h2 = h2buf + ((size_t)b*LSEG + l)*KH;
        float a0 = bv, a1 = 0.f, a2 = 0.f, a3 = 0.f;
#pragma unroll
        for (int j = 0; j < KH; j += 4) {
            a0 += w[j]*h2[j]; a1 += w[j+1]*h2[j+1];
            a2 += w[j+2]*h2[j+2]; a3 += w[j+3]*h2[j+3];
        }
        biasbuf[((size_t)b*LSEG + l)*BCH + rb] = (a0+a1)+(a2+a3);
    }
}

// ---------------- kernel generation (f16, dot2) ----------------------------
// kbuf[bl][o'][kk'] f16, o' = gate-interleave(o), kk' = tap*128 + c
// grid: 768 = tap(3) x blh(2) x o2(128); threads 256 = oh(2) x c(128)
// bl-half now lives in blockIdx -> h2h row addresses are BLOCK-UNIFORM:
// compiler can scalarize the h2 loads (s_load into SGPRs, scalar cache),
// and the prefetch double-buffer (32 v_mov/iter) is gone.
__global__ __launch_bounds__(256) void k_gen(const float* __restrict__ kW,
                                             const float* __restrict__ kb,
                                             const f16*   __restrict__ h2h,
                                             f16*         __restrict__ kbuf) {
    int tap = blockIdx.x >> 8;          // 0..2
    int rem = blockIdx.x & 255;
    int blh = rem >> 7;                 // block-uniform bl half
    int o2  = rem & 127;
    int c   = threadIdx.x & 127;
    int oh  = threadIdx.x >> 7;         // wave-uniform
    int o   = o2 + (oh << 7);           // 0..255
    int r   = (c*COUT + o)*KTAP + tap;
    f16x2 wh[32];
    const float4* wp = (const float4*)(kW + (size_t)r*KH);
#pragma unroll
    for (int q = 0; q < 16; ++q) {
        float4 v = wp[q];
        wh[2*q]   = f16x2{(f16)v.x, (f16)v.y};
        wh[2*q+1] = f16x2{(f16)v.z, (f16)v.w};
    }
    float kbv = kb[r];
    // gate-interleave: o<128 -> 2o ; o>=128 -> 2(o-128)+1  ==  2*o2 + oh
    int op = 2*o2 + oh;
    size_t obase = (size_t)op*384 + (size_t)tap*128 + c;
    int bl0 = blh*64;
    f16* kout = kbuf + (size_t)bl0*RPL + obase;
    const uint* h2p = (const uint*)(h2h + (size_t)bl0*KH);   // 32 uints per row, uniform addr
#pragma unroll 2
    for (int bl = 0; bl < 64; ++bl) {
        const uint* hr = h2p + bl*32;
        float a0 = kbv, a1 = 0.f, a2 = 0.f, a3 = 0.f;
#pragma unroll
        for (int q = 0; q < 8; ++q) {
            a0 = __builtin_amdgcn_fdot2(wh[4*q],   __builtin_bit_cast(f16x2, hr[4*q]),   a0, false);
            a1 = __builtin_amdgcn_fdot2(wh[4*q+1], __builtin_bit_cast(f16x2, hr[4*q+1]), a1, false);
            a2 = __builtin_amdgcn_fdot2(wh[4*q+2], __builtin_bit_cast(f16x2, hr[4*q+2]), a2, false);
            a3 = __builtin_amdgcn_fdot2(wh[4*q+3], __builtin_bit_cast(f16x2, hr[4*q+3]), a3, false);
        }
        kout[(size_t)bl*RPL] = (f16)((a0+a1)+(a2+a3));
    }
}

// ---------------- LVC layer via MFMA + fused gating (padded LDS, fewer barriers) ----
// grid = BB*LSEG*4; WG (b,l,oq) computes C[64 o' x 256 t] for one (b,l)
template<int DIL>
__global__ __launch_bounds__(256) void k_lvc(const f16* __restrict__ xin,
                                             const f16* __restrict__ kbuf,
                                             const float* __restrict__ biasbuf,
                                             f16* __restrict__ xout,
                                             int layerIdx) {
    constexpr int WIN = 256 + 2*DIL;
    int wg  = blockIdx.x;
    int o0  = (wg & 3)*64;
    int l   = (wg >> 2) & 63;
    int b   = wg >> 8;
    int bl  = b*LSEG + l;
    int tid = threadIdx.x;
    int w   = tid >> 6;
    int lane = tid & 63;
    int quad = lane >> 4;
    int n16  = lane & 15;
    int wo = (w & 1)*32;
    int wt = (w >> 1)*128;

    __shared__ f16 As[3*64*XS];        // [tap][o'_local][kk 32] padded
    __shared__ f16 xwin[288*XS];       // [tw][c] padded

    const float* bias_l = biasbuf + (size_t)bl*BCH + layerIdx*COUT;
    f32x4 acc[2][8];
#pragma unroll
    for (int j = 0; j < 2; ++j) {
        int g0 = (o0 + wo + j*16 + quad*4) >> 1;
        f32x4 ini;
        ini[0] = bias_l[g0];       ini[1] = bias_l[g0 + 128];
        ini[2] = bias_l[g0 + 1];   ini[3] = bias_l[g0 + 1 + 128];
#pragma unroll
        for (int tt = 0; tt < 8; ++tt) acc[j][tt] = ini;
    }

    const f16* xb = xin + (size_t)b*INNER*TT;
    const f16* kbl = kbuf + (size_t)bl*RPL + (size_t)o0*384;
    int o_l = tid >> 2, q4 = tid & 3;
    int gt0 = l*256 - DIL;

    for (int cb = 0; cb < 4; ++cb) {
        // stage x window (transposed, padded): wave w owns rows c = w, w+4, ..., w+28
        // incremental addressing, single unsigned bounds check — no division
        for (int cc = w; cc < 32; cc += 4) {
            const f16* src = xb + (size_t)(cb*32 + cc)*TT;
#pragma unroll
            for (int tw0 = 0; tw0 < WIN; tw0 += 64) {
                int tw = tw0 + lane;
                if (tw < WIN) {
                    int gt = gt0 + tw;
                    f16 v = ((unsigned)gt < (unsigned)TT) ? src[gt] : (f16)0.f;
                    xwin[tw*XS + cc] = v;
                }
            }
        }
#pragma unroll
        for (int tap = 0; tap < 3; ++tap) {
            f16x8 v = *(const f16x8*)&kbl[(size_t)o_l*384 + tap*128 + cb*32 + q4*8];
            *(f16x8*)&As[(tap*64 + o_l)*XS + q4*8] = v;
        }
        __syncthreads();
#pragma unroll
        for (int tap = 0; tap < 3; ++tap) {
            f16x8 af0 = *(const f16x8*)&As[(tap*64 + wo + n16)*XS + quad*8];
            f16x8 af1 = *(const f16x8*)&As[(tap*64 + wo + 16 + n16)*XS + quad*8];
#pragma unroll
            for (int tt = 0; tt < 8; ++tt) {
                int trow = wt + tt*16 + n16 + tap*DIL;
                f16x8 bf = *(const f16x8*)&xwin[trow*XS + quad*8];
                acc[0][tt] = __builtin_amdgcn_mfma_f32_16x16x32_f16(af0, bf, acc[0][tt], 0, 0, 0);
                acc[1][tt] = __builtin_amdgcn_mfma_f32_16x16x32_f16(af1, bf, acc[1][tt], 0, 0, 0);
            }
        }
        __syncthreads();
    }
    f16* ob = xout + (size_t)b*INNER*TT + l*256;
#pragma unroll
    for (int j = 0; j < 2; ++j) {
        int g0 = (o0 + wo + j*16 + quad*4) >> 1;
#pragma unroll
        for (int tt = 0; tt < 8; ++tt) {
            int tloc = wt + tt*16 + n16;
            f32x4 a = acc[j][tt];
            float s0  = 1.f/(1.f + __expf(-a[0]));
            float th0 = 2.f/(1.f + __expf(-2.f*a[1])) - 1.f;
            float s1  = 1.f/(1.f + __expf(-a[2]));
            float th1 = 2.f/(1.f + __expf(-2.f*a[3])) - 1.f;
            ob[(size_t)g0*TT + tloc]     = (f16)(s0*th0);
            ob[(size_t)(g0+1)*TT + tloc] = (f16)(s1*th1);
        }
    }
}

// ---------------- head: wave-uniform o-ranges -> scalar W1 loads ----------------
// grid = BB*TT/64 = 512; block: 64 t, 4 waves; wave w: o in [w*32, w*32+32)
__global__ __launch_bounds__(256) void k_head(const f16* __restrict__ y0,
                                              const f16* __restrict__ y1,
                                              const float* __restrict__ W1,
                                              const float* __restrict__ b1,
                                              const float* __restrict__ W2,
                                              const float* __restrict__ b2,
                                              float* __restrict__ out) {
    int b    = blockIdx.x >> 8;
    int tseg = (blockIdx.x & 255)*64;
    int tid  = threadIdx.x;
    int w    = tid >> 6;
    int lane = tid & 63;
    int t    = tseg + lane;
    __shared__ float red[4][64];

    float h[INNER];
    const f16* p0 = y0 + (size_t)b*INNER*TT + t;
    const f16* p1 = y1 + (size_t)b*INNER*TT + t;
#pragma unroll
    for (int c = 0; c < INNER; ++c) {
        float v = (float)p0[(size_t)c*TT] + (float)p1[(size_t)c*TT];
        h[c] = v > 0.f ? v : 0.f;
    }
    float part = 0.f;
    int oBase = w*32;
    for (int oi = 0; oi < 32; ++oi) {
        int o = oBase + oi;                      // wave-uniform
        const float* wr = W1 + o*INNER;          // -> s_load
        float z0 = b1[o], z1 = 0.f, z2 = 0.f, z3 = 0.f;
#pragma unroll
        for (int c = 0; c < INNER; c += 4) {
            z0 += wr[c]*h[c];   z1 += wr[c+1]*h[c+1];
            z2 += wr[c+2]*h[c+2]; z3 += wr[c+3]*h[c+3];
        }
        float z = (z0+z1)+(z2+z3);
        z = z > 0.f ? z : 0.f;
        part += W2[o]*z;
    }
    red[w][lane] = part;
    __syncthreads();
    if (w == 0) {
        float acc = b2[0] + red[0][lane] + red[1][lane] + red[2][lane] + red[3][lane];
        out[(size_t)b*TT + t] = acc;
    }
}

extern "C" void kernel_launch(void* const* d_in, const int* in_sizes, int n_in,
                              void* d_out, int out_size, void* d_ws, size_t ws_size,
                              hipStream_t stream) {
    const float* x    = (const float*)d_in[0];
    const float* c    = (const float*)d_in[1];
    const float* fcW  = (const float*)d_in[2];
    const float* fcb  = (const float*)d_in[3];
    const float* inpW = (const float*)d_in[4];
    const float* inpb = (const float*)d_in[5];
    const float* r1W  = (const float*)d_in[6];
    const float* r1b  = (const float*)d_in[7];
    const float* r2W  = (const float*)d_in[8];
    const float* r2b  = (const float*)d_in[9];
    const float* kW   = (const float*)d_in[10];
    const float* kb   = (const float*)d_in[11];
    const float* bW   = (const float*)d_in[12];
    const float* bb   = (const float*)d_in[13];
    const float* l1W  = (const float*)d_in[14];
    const float* l1b  = (const float*)d_in[15];
    const float* l2W  = (const float*)d_in[16];
    const float* l2b  = (const float*)d_in[17];

    float* ws = (float*)d_ws;
    float* h2buf   = ws;                                  // NBL*KH f32
    float* biasbuf = h2buf + (size_t)NBL*KH;              // NBL*BCH f32
    float* h1buf   = biasbuf + (size_t)NBL*BCH;           // BB*KH*LSEG f32
    f16*   h2h     = (f16*)(h1buf + (size_t)BB*KH*LSEG);  // NBL*KH f16
    f16*   bufA    = h2h + (size_t)NBL*KH;                // BB*INNER*TT f16 each
    f16*   bufB    = bufA + (size_t)BB*INNER*TT;
    f16*   bufC    = bufB + (size_t)BB*INNER*TT;
    f16*   kbuf    = bufC + (size_t)BB*INNER*TT;          // NBL*RPL f16

    k_fc<<<BB*TT/256*2, 256, 0, stream>>>(x, fcW, fcb, bufA);

    for (int n = 0; n < 2; ++n) {
        k_h1<<<BB*8, 256, 0, stream>>>(c, inpW + (size_t)n*KH*COND*5, inpb + n*KH, h1buf);
        k_h2t<<<BB, 256, 0, stream>>>(h1buf,
            r1W + n*KH*KH, r1b + n*KH,
            r2W + n*KH*KH, r2b + n*KH, h2buf, h2h);
        k_biash<<<(BB*BCH)/256, 256, 0, stream>>>(bW + (size_t)n*BCH*KH, bb + n*BCH,
                                                  h2buf, biasbuf);
        f16* pin = (n == 0) ? bufA : bufB;
        f16* s0  = (n == 0) ? bufB : bufC;
        f16* s1  = (n == 0) ? bufC : bufA;
        f16* cin = pin;
        for (int i = 0; i < LAYERS; ++i) {
            k_gen<<<768, 256, 0, stream>>>(
                kW + ((size_t)n*KCH + (size_t)i*RPL)*KH,
                kb + (size_t)n*KCH + (size_t)i*RPL,
                h2h, kbuf);
            f16* cout_ = (i % 2 == 0) ? s0 : s1;
            switch (i) {
                case 0: k_lvc<1> <<<BB*LSEG*4, 256, 0, stream>>>(cin, kbuf, biasbuf, cout_, i); break;
                case 1: k_lvc<2> <<<BB*LSEG*4, 256, 0, stream>>>(cin, kbuf, biasbuf, cout_, i); break;
                case 2: k_lvc<4> <<<BB*LSEG*4, 256, 0, stream>>>(cin, kbuf, biasbuf, cout_, i); break;
                case 3: k_lvc<8> <<<BB*LSEG*4, 256, 0, stream>>>(cin, kbuf, biasbuf, cout_, i); break;
                case 4: k_lvc<16><<<BB*LSEG*4, 256, 0, stream>>>(cin, kbuf, biasbuf, cout_, i); break;
            }
            cin = cout_;
        }
    }
    k_head<<<BB*TT/64, 256, 0, stream>>>(bufB, bufC, l1W, l1b, l2W, l2b, (float*)d_out);
}

// Round 2
// 1263.098 us; speedup vs baseline: 1.5001x; 1.0950x over previous
//
#include <hip/hip_runtime.h>
#include <math.h>

// ---------------- problem constants ----------------
#define BB     2
#define LSEG   64
#define HOP    256
#define TT     (LSEG*HOP)      // 16384
#define IN_CH  101
#define INNER  128
#define COND   81
#define LAYERS 5
#define KTAP   3
#define KH     64
#define COUT   256             // 2*INNER
#define RPL    (INNER*COUT*KTAP)   // 98304 rows per layer
#define KCH    (RPL*LAYERS)        // 491520
#define BCH    (COUT*LAYERS)       // 1280
#define NBL    (BB*LSEG)           // 128
#define XS     36                  // padded LDS row stride (f16) - bank stride 18

typedef _Float16 f16;
typedef _Float16 f16x2 __attribute__((ext_vector_type(2)));
typedef _Float16 f16x8 __attribute__((ext_vector_type(8)));
typedef float    f32x4 __attribute__((ext_vector_type(4)));

// ---------------- fc: h = fc_W @ x + fc_b -> f16 activations ----------------
__global__ __launch_bounds__(256) void k_fc(const float* __restrict__ x,
                                            const float* __restrict__ W,
                                            const float* __restrict__ bias,
                                            f16* __restrict__ out) {
    int half = blockIdx.x & 1;
    int g = (blockIdx.x >> 1)*256 + threadIdx.x;   // over BB*TT
    int b = g / TT, t = g % TT;
    float xv[IN_CH];
    const float* xp = x + (size_t)b*IN_CH*TT + t;
#pragma unroll
    for (int c = 0; c < IN_CH; ++c) xv[c] = xp[(size_t)c*TT];
    f16* op = out + (size_t)b*INNER*TT + t;
    int o0 = half*64;
    for (int o = o0; o < o0 + 64; ++o) {
        const float* wr = W + o*IN_CH;
        float a0 = bias[o], a1 = 0.f, a2 = 0.f, a3 = 0.f;
#pragma unroll
        for (int c = 0; c + 3 < IN_CH; c += 4) {
            a0 += wr[c]*xv[c]; a1 += wr[c+1]*xv[c+1];
            a2 += wr[c+2]*xv[c+2]; a3 += wr[c+3]*xv[c+3];
        }
        a0 += wr[100]*xv[100];
        op[(size_t)o*TT] = (f16)((a0+a1)+(a2+a3));
    }
}

// ---------------- predictor stage 1: h1 = lrelu(conv5(c)) ----------------
__global__ __launch_bounds__(256) void k_h1(const float* __restrict__ cc,
                                            const float* __restrict__ iW,
                                            const float* __restrict__ ib,
                                            float* __restrict__ h1buf) {
    int og = blockIdx.x & 7;
    int b  = blockIdx.x >> 3;
    __shared__ float cL[COND*LSEG];
    __shared__ float wL[8*COND*5];
    int tid = threadIdx.x;
    for (int idx = tid; idx < COND*LSEG; idx += 256)
        cL[idx] = cc[(size_t)b*COND*LSEG + idx];
    const float* wsrc = iW + (size_t)og*8*COND*5;
    for (int idx = tid; idx < 8*COND*5; idx += 256)
        wL[idx] = wsrc[idx];
    __syncthreads();
#pragma unroll
    for (int rep = 0; rep < 2; ++rep) {
        int idx = rep*256 + tid;
        int ol = idx >> 6, l = idx & 63;
        int o  = og*8 + ol;
        float acc = ib[o];
        const float* wrow = wL + ol*COND*5;
        for (int i = 0; i < COND; ++i) {
            const float* crow = cL + i*LSEG;
            const float* w5 = wrow + i*5;
#pragma unroll
            for (int k = 0; k < 5; ++k) {
                int ll = l + k - 2;
                if (ll >= 0 && ll < LSEG) acc += crow[ll]*w5[k];
            }
        }
        h1buf[((size_t)b*KH + o)*LSEG + l] = acc >= 0.f ? acc : 0.1f*acc;
    }
}

// ---------------- predictor stage 2: h2 (f32 for bias head, f16 for k_gen) ----------------
__global__ __launch_bounds__(256) void k_h2t(const float* __restrict__ h1buf,
                                             const float* __restrict__ r1W,
                                             const float* __restrict__ r1b,
                                             const float* __restrict__ r2W,
                                             const float* __restrict__ r2b,
                                             float* __restrict__ h2buf,
                                             f16* __restrict__ h2h) {
    int b = blockIdx.x;
    __shared__ float h1L[KH*LSEG];
    __shared__ float t1L[KH*LSEG];
    __shared__ float wL[KH*KH];
    int tid = threadIdx.x;
    for (int idx = tid; idx < KH*LSEG; idx += 256)
        h1L[idx] = h1buf[(size_t)b*KH*LSEG + idx];
    for (int idx = tid; idx < KH*KH; idx += 256)
        wL[idx] = r1W[idx];
    __syncthreads();
#pragma unroll
    for (int rep = 0; rep < 16; ++rep) {
        int idx = rep*256 + tid;
        int o = idx >> 6, l = idx & 63;
        float acc = r1b[o];
        const float* wr = wL + o*KH;
#pragma unroll
        for (int i = 0; i < KH; ++i) acc += wr[i]*h1L[i*LSEG + l];
        t1L[idx] = acc >= 0.f ? acc : 0.1f*acc;
    }
    __syncthreads();
    for (int idx = tid; idx < KH*KH; idx += 256)
        wL[idx] = r2W[idx];
    __syncthreads();
#pragma unroll
    for (int rep = 0; rep < 16; ++rep) {
        int idx = rep*256 + tid;
        int o = idx >> 6, l = idx & 63;
        float acc = r2b[o];
        const float* wr = wL + o*KH;
#pragma unroll
        for (int i = 0; i < KH; ++i) acc += wr[i]*t1L[i*LSEG + l];
        float h2 = h1L[o*LSEG + l] + acc;
        h2buf[((size_t)b*LSEG + l)*KH + o] = h2;           // [bl][o] f32
        h2h  [((size_t)b*LSEG + l)*KH + o] = (f16)h2;      // [bl][o] f16
    }
}

// ---------------- bias head (separate tiny kernel, once per n-block) ----------------
__global__ __launch_bounds__(256) void k_biash(const float* __restrict__ bW,
                                               const float* __restrict__ bb,
                                               const float* __restrict__ h2buf,
                                               float* __restrict__ biasbuf) {
    int tg = blockIdx.x*256 + threadIdx.x;       // 0..2559
    int b  = __builtin_amdgcn_readfirstlane(tg / BCH);
    int rb = tg % BCH;
    float w[KH];
    const float4* wp = (const float4*)(bW + (size_t)rb*KH);
#pragma unroll
    for (int q = 0; q < KH/4; ++q) {
        float4 v = wp[q];
        w[4*q] = v.x; w[4*q+1] = v.y; w[4*q+2] = v.z; w[4*q+3] = v.w;
    }
    float bv = bb[rb];
    for (int l = 0; l < LSEG; ++l) {
        const float* h2 = h2buf + ((size_t)b*LSEG + l)*KH;
        float a0 = bv, a1 = 0.f, a2 = 0.f, a3 = 0.f;
#pragma unroll
        for (int j = 0; j < KH; j += 4) {
            a0 += w[j]*h2[j]; a1 += w[j+1]*h2[j+1];
            a2 += w[j+2]*h2[j+2]; a3 += w[j+3]*h2[j+3];
        }
        biasbuf[((size_t)b*LSEG + l)*BCH + rb] = (a0+a1)+(a2+a3);
    }
}

// ---------------- kernel generation (f16, dot2), ALL 5 LAYERS in one launch ----
// kbuf[layer][bl][o'][kk'] f16, o' = gate-interleave(o), kk' = tap*128 + c
// grid: 3840 = layer(5) x tap(3) x blh(2) x o2(128); threads 256 = oh(2) x c(128)
// Merged launch: 15360 waves -> ~5-6 waves/SIMD resident (vs 3 before) so the
// 64-line kW row-gather latency is hidden by TLP. h2h rows stay block-uniform
// -> s_load scalarization retained.
__global__ __launch_bounds__(256) void k_gen(const float* __restrict__ kW,
                                             const float* __restrict__ kb,
                                             const f16*   __restrict__ h2h,
                                             f16*         __restrict__ kbuf) {
    int lay = blockIdx.x / 768;         // 0..4 (uniform)
    int blk = blockIdx.x - lay*768;
    int tap = blk >> 8;                 // 0..2
    int rem = blk & 255;
    int blh = rem >> 7;                 // block-uniform bl half
    int o2  = rem & 127;
    int c   = threadIdx.x & 127;
    int oh  = threadIdx.x >> 7;         // wave-uniform
    int o   = o2 + (oh << 7);           // 0..255
    size_t r = (size_t)lay*RPL + (size_t)((c*COUT + o)*KTAP + tap);
    f16x2 wh[32];
    const float4* wp = (const float4*)(kW + r*KH);
#pragma unroll
    for (int q = 0; q < 16; ++q) {
        float4 v = wp[q];
        wh[2*q]   = f16x2{(f16)v.x, (f16)v.y};
        wh[2*q+1] = f16x2{(f16)v.z, (f16)v.w};
    }
    float kbv = kb[r];
    // gate-interleave: o<128 -> 2o ; o>=128 -> 2(o-128)+1  ==  2*o2 + oh
    int op = 2*o2 + oh;
    size_t obase = (size_t)op*384 + (size_t)tap*128 + c;
    int bl0 = blh*64;
    f16* kout = kbuf + ((size_t)lay*NBL + bl0)*RPL + obase;
    const uint* h2p = (const uint*)(h2h + (size_t)bl0*KH);   // uniform addr -> s_load
#pragma unroll 2
    for (int bl = 0; bl < 64; ++bl) {
        const uint* hr = h2p + bl*32;
        float a0 = kbv, a1 = 0.f, a2 = 0.f, a3 = 0.f;
#pragma unroll
        for (int q = 0; q < 8; ++q) {
            a0 = __builtin_amdgcn_fdot2(wh[4*q],   __builtin_bit_cast(f16x2, hr[4*q]),   a0, false);
            a1 = __builtin_amdgcn_fdot2(wh[4*q+1], __builtin_bit_cast(f16x2, hr[4*q+1]), a1, false);
            a2 = __builtin_amdgcn_fdot2(wh[4*q+2], __builtin_bit_cast(f16x2, hr[4*q+2]), a2, false);
            a3 = __builtin_amdgcn_fdot2(wh[4*q+3], __builtin_bit_cast(f16x2, hr[4*q+3]), a3, false);
        }
        kout[(size_t)bl*RPL] = (f16)((a0+a1)+(a2+a3));
    }
}

// ---------------- LVC layer via MFMA + fused gating (padded LDS, fewer barriers) ----
// grid = BB*LSEG*4; WG (b,l,oq) computes C[64 o' x 256 t] for one (b,l)
template<int DIL>
__global__ __launch_bounds__(256) void k_lvc(const f16* __restrict__ xin,
                                             const f16* __restrict__ kbuf,
                                             const float* __restrict__ biasbuf,
                                             f16* __restrict__ xout,
                                             int layerIdx) {
    constexpr int WIN = 256 + 2*DIL;
    int wg  = blockIdx.x;
    int o0  = (wg & 3)*64;
    int l   = (wg >> 2) & 63;
    int b   = wg >> 8;
    int bl  = b*LSEG + l;
    int tid = threadIdx.x;
    int w   = tid >> 6;
    int lane = tid & 63;
    int quad = lane >> 4;
    int n16  = lane & 15;
    int wo = (w & 1)*32;
    int wt = (w >> 1)*128;

    __shared__ f16 As[3*64*XS];        // [tap][o'_local][kk 32] padded
    __shared__ f16 xwin[288*XS];       // [tw][c] padded

    const float* bias_l = biasbuf + (size_t)bl*BCH + layerIdx*COUT;
    f32x4 acc[2][8];
#pragma unroll
    for (int j = 0; j < 2; ++j) {
        int g0 = (o0 + wo + j*16 + quad*4) >> 1;
        f32x4 ini;
        ini[0] = bias_l[g0];       ini[1] = bias_l[g0 + 128];
        ini[2] = bias_l[g0 + 1];   ini[3] = bias_l[g0 + 1 + 128];
#pragma unroll
        for (int tt = 0; tt < 8; ++tt) acc[j][tt] = ini;
    }

    const f16* xb = xin + (size_t)b*INNER*TT;
    const f16* kbl = kbuf + (size_t)bl*RPL + (size_t)o0*384;
    int o_l = tid >> 2, q4 = tid & 3;
    int gt0 = l*256 - DIL;

    for (int cb = 0; cb < 4; ++cb) {
        // stage x window (transposed, padded): wave w owns rows c = w, w+4, ..., w+28
        // incremental addressing, single unsigned bounds check — no division
        for (int cc = w; cc < 32; cc += 4) {
            const f16* src = xb + (size_t)(cb*32 + cc)*TT;
#pragma unroll
            for (int tw0 = 0; tw0 < WIN; tw0 += 64) {
                int tw = tw0 + lane;
                if (tw < WIN) {
                    int gt = gt0 + tw;
                    f16 v = ((unsigned)gt < (unsigned)TT) ? src[gt] : (f16)0.f;
                    xwin[tw*XS + cc] = v;
                }
            }
        }
#pragma unroll
        for (int tap = 0; tap < 3; ++tap) {
            f16x8 v = *(const f16x8*)&kbl[(size_t)o_l*384 + tap*128 + cb*32 + q4*8];
            *(f16x8*)&As[(tap*64 + o_l)*XS + q4*8] = v;
        }
        __syncthreads();
#pragma unroll
        for (int tap = 0; tap < 3; ++tap) {
            f16x8 af0 = *(const f16x8*)&As[(tap*64 + wo + n16)*XS + quad*8];
            f16x8 af1 = *(const f16x8*)&As[(tap*64 + wo + 16 + n16)*XS + quad*8];
#pragma unroll
            for (int tt = 0; tt < 8; ++tt) {
                int trow = wt + tt*16 + n16 + tap*DIL;
                f16x8 bf = *(const f16x8*)&xwin[trow*XS + quad*8];
                acc[0][tt] = __builtin_amdgcn_mfma_f32_16x16x32_f16(af0, bf, acc[0][tt], 0, 0, 0);
                acc[1][tt] = __builtin_amdgcn_mfma_f32_16x16x32_f16(af1, bf, acc[1][tt], 0, 0, 0);
            }
        }
        __syncthreads();
    }
    f16* ob = xout + (size_t)b*INNER*TT + l*256;
#pragma unroll
    for (int j = 0; j < 2; ++j) {
        int g0 = (o0 + wo + j*16 + quad*4) >> 1;
#pragma unroll
        for (int tt = 0; tt < 8; ++tt) {
            int tloc = wt + tt*16 + n16;
            f32x4 a = acc[j][tt];
            float s0  = 1.f/(1.f + __expf(-a[0]));
            float th0 = 2.f/(1.f + __expf(-2.f*a[1])) - 1.f;
            float s1  = 1.f/(1.f + __expf(-a[2]));
            float th1 = 2.f/(1.f + __expf(-2.f*a[3])) - 1.f;
            ob[(size_t)g0*TT + tloc]     = (f16)(s0*th0);
            ob[(size_t)(g0+1)*TT + tloc] = (f16)(s1*th1);
        }
    }
}

// ---------------- head: wave-uniform o-ranges -> scalar W1 loads ----------------
// grid = BB*TT/64 = 512; block: 64 t, 4 waves; wave w: o in [w*32, w*32+32)
__global__ __launch_bounds__(256) void k_head(const f16* __restrict__ y0,
                                              const f16* __restrict__ y1,
                                              const float* __restrict__ W1,
                                              const float* __restrict__ b1,
                                              const float* __restrict__ W2,
                                              const float* __restrict__ b2,
                                              float* __restrict__ out) {
    int b    = blockIdx.x >> 8;
    int tseg = (blockIdx.x & 255)*64;
    int tid  = threadIdx.x;
    int w    = tid >> 6;
    int lane = tid & 63;
    int t    = tseg + lane;
    __shared__ float red[4][64];

    float h[INNER];
    const f16* p0 = y0 + (size_t)b*INNER*TT + t;
    const f16* p1 = y1 + (size_t)b*INNER*TT + t;
#pragma unroll
    for (int c = 0; c < INNER; ++c) {
        float v = (float)p0[(size_t)c*TT] + (float)p1[(size_t)c*TT];
        h[c] = v > 0.f ? v : 0.f;
    }
    float part = 0.f;
    int oBase = w*32;
    for (int oi = 0; oi < 32; ++oi) {
        int o = oBase + oi;                      // wave-uniform
        const float* wr = W1 + o*INNER;          // -> s_load
        float z0 = b1[o], z1 = 0.f, z2 = 0.f, z3 = 0.f;
#pragma unroll
        for (int c = 0; c < INNER; c += 4) {
            z0 += wr[c]*h[c];   z1 += wr[c+1]*h[c+1];
            z2 += wr[c+2]*h[c+2]; z3 += wr[c+3]*h[c+3];
        }
        float z = (z0+z1)+(z2+z3);
        z = z > 0.f ? z : 0.f;
        part += W2[o]*z;
    }
    red[w][lane] = part;
    __syncthreads();
    if (w == 0) {
        float acc = b2[0] + red[0][lane] + red[1][lane] + red[2][lane] + red[3][lane];
        out[(size_t)b*TT + t] = acc;
    }
}

extern "C" void kernel_launch(void* const* d_in, const int* in_sizes, int n_in,
                              void* d_out, int out_size, void* d_ws, size_t ws_size,
                              hipStream_t stream) {
    const float* x    = (const float*)d_in[0];
    const float* c    = (const float*)d_in[1];
    const float* fcW  = (const float*)d_in[2];
    const float* fcb  = (const float*)d_in[3];
    const float* inpW = (const float*)d_in[4];
    const float* inpb = (const float*)d_in[5];
    const float* r1W  = (const float*)d_in[6];
    const float* r1b  = (const float*)d_in[7];
    const float* r2W  = (const float*)d_in[8];
    const float* r2b  = (const float*)d_in[9];
    const float* kW   = (const float*)d_in[10];
    const float* kb   = (const float*)d_in[11];
    const float* bW   = (const float*)d_in[12];
    const float* bb   = (const float*)d_in[13];
    const float* l1W  = (const float*)d_in[14];
    const float* l1b  = (const float*)d_in[15];
    const float* l2W  = (const float*)d_in[16];
    const float* l2b  = (const float*)d_in[17];

    float* ws = (float*)d_ws;
    float* h2buf   = ws;                                  // NBL*KH f32
    float* biasbuf = h2buf + (size_t)NBL*KH;              // NBL*BCH f32
    float* h1buf   = biasbuf + (size_t)NBL*BCH;           // BB*KH*LSEG f32
    f16*   h2h     = (f16*)(h1buf + (size_t)BB*KH*LSEG);  // NBL*KH f16
    f16*   bufA    = h2h + (size_t)NBL*KH;                // BB*INNER*TT f16 each
    f16*   bufB    = bufA + (size_t)BB*INNER*TT;
    f16*   bufC    = bufB + (size_t)BB*INNER*TT;
    f16*   kbuf    = bufC + (size_t)BB*INNER*TT;          // LAYERS*NBL*RPL f16

    k_fc<<<BB*TT/256*2, 256, 0, stream>>>(x, fcW, fcb, bufA);

    for (int n = 0; n < 2; ++n) {
        k_h1<<<BB*8, 256, 0, stream>>>(c, inpW + (size_t)n*KH*COND*5, inpb + n*KH, h1buf);
        k_h2t<<<BB, 256, 0, stream>>>(h1buf,
            r1W + n*KH*KH, r1b + n*KH,
            r2W + n*KH*KH, r2b + n*KH, h2buf, h2h);
        k_biash<<<(BB*BCH)/256, 256, 0, stream>>>(bW + (size_t)n*BCH*KH, bb + n*BCH,
                                                  h2buf, biasbuf);
        // ALL 5 layers' kernel generation in one launch (depends only on h2h)
        k_gen<<<5*768, 256, 0, stream>>>(
            kW + (size_t)n*KCH*KH,
            kb + (size_t)n*KCH,
            h2h, kbuf);
        f16* pin = (n == 0) ? bufA : bufB;
        f16* s0  = (n == 0) ? bufB : bufC;
        f16* s1  = (n == 0) ? bufC : bufA;
        f16* cin = pin;
        for (int i = 0; i < LAYERS; ++i) {
            const f16* kslice = kbuf + (size_t)i*NBL*RPL;
            f16* cout_ = (i % 2 == 0) ? s0 : s1;
            switch (i) {
                case 0: k_lvc<1> <<<BB*LSEG*4, 256, 0, stream>>>(cin, kslice, biasbuf, cout_, i); break;
                case 1: k_lvc<2> <<<BB*LSEG*4, 256, 0, stream>>>(cin, kslice, biasbuf, cout_, i); break;
                case 2: k_lvc<4> <<<BB*LSEG*4, 256, 0, stream>>>(cin, kslice, biasbuf, cout_, i); break;
                case 3: k_lvc<8> <<<BB*LSEG*4, 256, 0, stream>>>(cin, kslice, biasbuf, cout_, i); break;
                case 4: k_lvc<16><<<BB*LSEG*4, 256, 0, stream>>>(cin, kslice, biasbuf, cout_, i); break;
            }
            cin = cout_;
        }
    }
    k_head<<<BB*TT/64, 256, 0, stream>>>(bufB, bufC, l1W, l1b, l2W, l2b, (float*)d_out);
}

// Round 3
// 1176.044 us; speedup vs baseline: 1.6112x; 1.0740x over previous
//
#include <hip/hip_runtime.h>
#include <math.h>

// ---------------- problem constants ----------------
#define BB     2
#define LSEG   64
#define HOP    256
#define TT     (LSEG*HOP)      // 16384
#define IN_CH  101
#define INNER  128
#define COND   81
#define LAYERS 5
#define KTAP   3
#define KH     64
#define COUT   256             // 2*INNER
#define RPL    (INNER*COUT*KTAP)   // 98304 rows per layer
#define KCH    (RPL*LAYERS)        // 491520
#define BCH    (COUT*LAYERS)       // 1280
#define NBL    (BB*LSEG)           // 128
#define XS     36                  // padded LDS row stride (f16) - bank stride 18

typedef _Float16 f16;
typedef _Float16 f16x2 __attribute__((ext_vector_type(2)));
typedef _Float16 f16x8 __attribute__((ext_vector_type(8)));
typedef float    f32x4 __attribute__((ext_vector_type(4)));

// ---------------- fc: h = fc_W @ x + fc_b -> f16 activations ----------------
__global__ __launch_bounds__(256) void k_fc(const float* __restrict__ x,
                                            const float* __restrict__ W,
                                            const float* __restrict__ bias,
                                            f16* __restrict__ out) {
    int half = blockIdx.x & 1;
    int g = (blockIdx.x >> 1)*256 + threadIdx.x;   // over BB*TT
    int b = g / TT, t = g % TT;
    float xv[IN_CH];
    const float* xp = x + (size_t)b*IN_CH*TT + t;
#pragma unroll
    for (int c = 0; c < IN_CH; ++c) xv[c] = xp[(size_t)c*TT];
    f16* op = out + (size_t)b*INNER*TT + t;
    int o0 = half*64;
    for (int o = o0; o < o0 + 64; ++o) {
        const float* wr = W + o*IN_CH;
        float a0 = bias[o], a1 = 0.f, a2 = 0.f, a3 = 0.f;
#pragma unroll
        for (int c = 0; c + 3 < IN_CH; c += 4) {
            a0 += wr[c]*xv[c]; a1 += wr[c+1]*xv[c+1];
            a2 += wr[c+2]*xv[c+2]; a3 += wr[c+3]*xv[c+3];
        }
        a0 += wr[100]*xv[100];
        op[(size_t)o*TT] = (f16)((a0+a1)+(a2+a3));
    }
}

// ---------------- predictor stage 1: h1 = lrelu(conv5(c)), BOTH n-blocks ----
// grid 32 = n(2) x b(2) x og(8)
__global__ __launch_bounds__(256) void k_h1(const float* __restrict__ cc,
                                            const float* __restrict__ iW,
                                            const float* __restrict__ ib,
                                            float* __restrict__ h1buf) {
    int og = blockIdx.x & 7;
    int bp = blockIdx.x >> 3;        // 0..3
    int b  = bp & 1;
    int n  = bp >> 1;
    __shared__ float cL[COND*LSEG];
    __shared__ float wL[8*COND*5];
    int tid = threadIdx.x;
    for (int idx = tid; idx < COND*LSEG; idx += 256)
        cL[idx] = cc[(size_t)b*COND*LSEG + idx];
    const float* wsrc = iW + (size_t)n*KH*COND*5 + (size_t)og*8*COND*5;
    for (int idx = tid; idx < 8*COND*5; idx += 256)
        wL[idx] = wsrc[idx];
    __syncthreads();
#pragma unroll
    for (int rep = 0; rep < 2; ++rep) {
        int idx = rep*256 + tid;
        int ol = idx >> 6, l = idx & 63;
        int o  = og*8 + ol;
        float acc = ib[n*KH + o];
        const float* wrow = wL + ol*COND*5;
        for (int i = 0; i < COND; ++i) {
            const float* crow = cL + i*LSEG;
            const float* w5 = wrow + i*5;
#pragma unroll
            for (int k = 0; k < 5; ++k) {
                int ll = l + k - 2;
                if (ll >= 0 && ll < LSEG) acc += crow[ll]*w5[k];
            }
        }
        h1buf[(((size_t)(n*BB + b))*KH + o)*LSEG + l] = acc >= 0.f ? acc : 0.1f*acc;
    }
}

// ---------------- predictor stage 2: h2, BOTH n-blocks ----------------------
// grid 4 = n(2) x b(2)
__global__ __launch_bounds__(256) void k_h2t(const float* __restrict__ h1buf,
                                             const float* __restrict__ r1W,
                                             const float* __restrict__ r1b,
                                             const float* __restrict__ r2W,
                                             const float* __restrict__ r2b,
                                             float* __restrict__ h2buf,
                                             f16* __restrict__ h2h) {
    int b = blockIdx.x & 1;
    int n = blockIdx.x >> 1;
    __shared__ float h1L[KH*LSEG];
    __shared__ float t1L[KH*LSEG];
    __shared__ float wL[KH*KH];
    int tid = threadIdx.x;
    const float* h1src = h1buf + ((size_t)(n*BB + b))*KH*LSEG;
    for (int idx = tid; idx < KH*LSEG; idx += 256)
        h1L[idx] = h1src[idx];
    for (int idx = tid; idx < KH*KH; idx += 256)
        wL[idx] = r1W[(size_t)n*KH*KH + idx];
    __syncthreads();
#pragma unroll
    for (int rep = 0; rep < 16; ++rep) {
        int idx = rep*256 + tid;
        int o = idx >> 6, l = idx & 63;
        float acc = r1b[n*KH + o];
        const float* wr = wL + o*KH;
#pragma unroll
        for (int i = 0; i < KH; ++i) acc += wr[i]*h1L[i*LSEG + l];
        t1L[idx] = acc >= 0.f ? acc : 0.1f*acc;
    }
    __syncthreads();
    for (int idx = tid; idx < KH*KH; idx += 256)
        wL[idx] = r2W[(size_t)n*KH*KH + idx];
    __syncthreads();
#pragma unroll
    for (int rep = 0; rep < 16; ++rep) {
        int idx = rep*256 + tid;
        int o = idx >> 6, l = idx & 63;
        float acc = r2b[n*KH + o];
        const float* wr = wL + o*KH;
#pragma unroll
        for (int i = 0; i < KH; ++i) acc += wr[i]*t1L[i*LSEG + l];
        float h2 = h1L[o*LSEG + l] + acc;
        size_t row = (size_t)n*NBL + b*LSEG + l;
        h2buf[row*KH + o] = h2;           // [n][bl][o] f32
        h2h  [row*KH + o] = (f16)h2;      // [n][bl][o] f16
    }
}

// ---------------- bias head, BOTH n-blocks ----------------------------------
// grid 20 = 2*BB*BCH/256
__global__ __launch_bounds__(256) void k_biash(const float* __restrict__ bW,
                                               const float* __restrict__ bb,
                                               const float* __restrict__ h2buf,
                                               float* __restrict__ biasbuf) {
    int tg = blockIdx.x*256 + threadIdx.x;       // 0..5119
    int n  = __builtin_amdgcn_readfirstlane(tg / (BB*BCH));
    int rem = tg - n*(BB*BCH);
    int b  = __builtin_amdgcn_readfirstlane(rem / BCH);
    int rb = rem % BCH;
    float w[KH];
    const float4* wp = (const float4*)(bW + ((size_t)n*BCH + rb)*KH);
#pragma unroll
    for (int q = 0; q < KH/4; ++q) {
        float4 v = wp[q];
        w[4*q] = v.x; w[4*q+1] = v.y; w[4*q+2] = v.z; w[4*q+3] = v.w;
    }
    float bv = bb[n*BCH + rb];
    for (int l = 0; l < LSEG; ++l) {
        size_t row = (size_t)n*NBL + b*LSEG + l;
        const float* h2 = h2buf + row*KH;
        float a0 = bv, a1 = 0.f, a2 = 0.f, a3 = 0.f;
#pragma unroll
        for (int j = 0; j < KH; j += 4) {
            a0 += w[j]*h2[j]; a1 += w[j+1]*h2[j+1];
            a2 += w[j+2]*h2[j+2]; a3 += w[j+3]*h2[j+3];
        }
        biasbuf[row*BCH + rb] = (a0+a1)+(a2+a3);
    }
}

// ---------------- kernel generation: ALL layers, BOTH n-blocks, one launch ----
// kbuf[n][layer][bl][o'][kk'] f16, o' = gate-interleave(o), kk' = tap*128 + c
// grid: 3840 = n(2) x lay(5) x tap(3) x o2(128); threads 256 = oh(2) x c(128)
// Each block now covers ALL 128 bl -> every kW row fetched exactly ONCE.
// h2h rows are block-uniform -> s_load scalarization retained.
__global__ __launch_bounds__(256) void k_gen(const float* __restrict__ kW,
                                             const float* __restrict__ kb,
                                             const f16*   __restrict__ h2h,
                                             f16*         __restrict__ kbuf) {
    int o2  = blockIdx.x & 127;
    int tmp = blockIdx.x >> 7;
    int tap = tmp % 3;
    int tmp2 = tmp / 3;
    int lay = tmp2 % 5;
    int n   = tmp2 / 5;
    int c   = threadIdx.x & 127;
    int oh  = threadIdx.x >> 7;         // wave-uniform
    int o   = o2 + (oh << 7);           // 0..255
    size_t r = (size_t)lay*RPL + (size_t)((c*COUT + o)*KTAP + tap);
    f16x2 wh[32];
    const float4* wp = (const float4*)(kW + ((size_t)n*KCH + r)*KH);
#pragma unroll
    for (int q = 0; q < 16; ++q) {
        float4 v = wp[q];
        wh[2*q]   = f16x2{(f16)v.x, (f16)v.y};
        wh[2*q+1] = f16x2{(f16)v.z, (f16)v.w};
    }
    float kbv = kb[(size_t)n*KCH + r];
    // gate-interleave: o<128 -> 2o ; o>=128 -> 2(o-128)+1  ==  2*o2 + oh
    int op = 2*o2 + oh;
    size_t obase = (size_t)op*384 + (size_t)tap*128 + c;
    f16* kout = kbuf + ((size_t)(n*LAYERS + lay)*NBL)*RPL + obase;
    const uint* h2p = (const uint*)(h2h + (size_t)n*NBL*KH);   // uniform addr -> s_load
#pragma unroll 2
    for (int bl = 0; bl < NBL; ++bl) {
        const uint* hr = h2p + bl*32;
        float a0 = kbv, a1 = 0.f, a2 = 0.f, a3 = 0.f;
#pragma unroll
        for (int q = 0; q < 8; ++q) {
            a0 = __builtin_amdgcn_fdot2(wh[4*q],   __builtin_bit_cast(f16x2, hr[4*q]),   a0, false);
            a1 = __builtin_amdgcn_fdot2(wh[4*q+1], __builtin_bit_cast(f16x2, hr[4*q+1]), a1, false);
            a2 = __builtin_amdgcn_fdot2(wh[4*q+2], __builtin_bit_cast(f16x2, hr[4*q+2]), a2, false);
            a3 = __builtin_amdgcn_fdot2(wh[4*q+3], __builtin_bit_cast(f16x2, hr[4*q+3]), a3, false);
        }
        kout[(size_t)bl*RPL] = (f16)((a0+a1)+(a2+a3));
    }
}

// ---------------- LVC layer via MFMA + fused gating (padded LDS, fewer barriers) ----
// grid = BB*LSEG*4; WG (b,l,oq) computes C[64 o' x 256 t] for one (b,l)
template<int DIL>
__global__ __launch_bounds__(256) void k_lvc(const f16* __restrict__ xin,
                                             const f16* __restrict__ kbuf,
                                             const float* __restrict__ biasbuf,
                                             f16* __restrict__ xout,
                                             int layerIdx) {
    constexpr int WIN = 256 + 2*DIL;
    int wg  = blockIdx.x;
    int o0  = (wg & 3)*64;
    int l   = (wg >> 2) & 63;
    int b   = wg >> 8;
    int bl  = b*LSEG + l;
    int tid = threadIdx.x;
    int w   = tid >> 6;
    int lane = tid & 63;
    int quad = lane >> 4;
    int n16  = lane & 15;
    int wo = (w & 1)*32;
    int wt = (w >> 1)*128;

    __shared__ f16 As[3*64*XS];        // [tap][o'_local][kk 32] padded
    __shared__ f16 xwin[288*XS];       // [tw][c] padded

    const float* bias_l = biasbuf + (size_t)bl*BCH + layerIdx*COUT;
    f32x4 acc[2][8];
#pragma unroll
    for (int j = 0; j < 2; ++j) {
        int g0 = (o0 + wo + j*16 + quad*4) >> 1;
        f32x4 ini;
        ini[0] = bias_l[g0];       ini[1] = bias_l[g0 + 128];
        ini[2] = bias_l[g0 + 1];   ini[3] = bias_l[g0 + 1 + 128];
#pragma unroll
        for (int tt = 0; tt < 8; ++tt) acc[j][tt] = ini;
    }

    const f16* xb = xin + (size_t)b*INNER*TT;
    const f16* kbl = kbuf + (size_t)bl*RPL + (size_t)o0*384;
    int o_l = tid >> 2, q4 = tid & 3;
    int gt0 = l*256 - DIL;

    for (int cb = 0; cb < 4; ++cb) {
        // stage x window (transposed, padded): wave w owns rows c = w, w+4, ..., w+28
        for (int cc = w; cc < 32; cc += 4) {
            const f16* src = xb + (size_t)(cb*32 + cc)*TT;
#pragma unroll
            for (int tw0 = 0; tw0 < WIN; tw0 += 64) {
                int tw = tw0 + lane;
                if (tw < WIN) {
                    int gt = gt0 + tw;
                    f16 v = ((unsigned)gt < (unsigned)TT) ? src[gt] : (f16)0.f;
                    xwin[tw*XS + cc] = v;
                }
            }
        }
#pragma unroll
        for (int tap = 0; tap < 3; ++tap) {
            f16x8 v = *(const f16x8*)&kbl[(size_t)o_l*384 + tap*128 + cb*32 + q4*8];
            *(f16x8*)&As[(tap*64 + o_l)*XS + q4*8] = v;
        }
        __syncthreads();
#pragma unroll
        for (int tap = 0; tap < 3; ++tap) {
            f16x8 af0 = *(const f16x8*)&As[(tap*64 + wo + n16)*XS + quad*8];
            f16x8 af1 = *(const f16x8*)&As[(tap*64 + wo + 16 + n16)*XS + quad*8];
#pragma unroll
            for (int tt = 0; tt < 8; ++tt) {
                int trow = wt + tt*16 + n16 + tap*DIL;
                f16x8 bf = *(const f16x8*)&xwin[trow*XS + quad*8];
                acc[0][tt] = __builtin_amdgcn_mfma_f32_16x16x32_f16(af0, bf, acc[0][tt], 0, 0, 0);
                acc[1][tt] = __builtin_amdgcn_mfma_f32_16x16x32_f16(af1, bf, acc[1][tt], 0, 0, 0);
            }
        }
        __syncthreads();
    }
    f16* ob = xout + (size_t)b*INNER*TT + l*256;
#pragma unroll
    for (int j = 0; j < 2; ++j) {
        int g0 = (o0 + wo + j*16 + quad*4) >> 1;
#pragma unroll
        for (int tt = 0; tt < 8; ++tt) {
            int tloc = wt + tt*16 + n16;
            f32x4 a = acc[j][tt];
            float s0  = 1.f/(1.f + __expf(-a[0]));
            float th0 = 2.f/(1.f + __expf(-2.f*a[1])) - 1.f;
            float s1  = 1.f/(1.f + __expf(-a[2]));
            float th1 = 2.f/(1.f + __expf(-2.f*a[3])) - 1.f;
            ob[(size_t)g0*TT + tloc]     = (f16)(s0*th0);
            ob[(size_t)(g0+1)*TT + tloc] = (f16)(s1*th1);
        }
    }
}

// ---------------- head: wave-uniform o-ranges -> scalar W1 loads ----------------
__global__ __launch_bounds__(256) void k_head(const f16* __restrict__ y0,
                                              const f16* __restrict__ y1,
                                              const float* __restrict__ W1,
                                              const float* __restrict__ b1,
                                              const float* __restrict__ W2,
                                              const float* __restrict__ b2,
                                              float* __restrict__ out) {
    int b    = blockIdx.x >> 8;
    int tseg = (blockIdx.x & 255)*64;
    int tid  = threadIdx.x;
    int w    = tid >> 6;
    int lane = tid & 63;
    int t    = tseg + lane;
    __shared__ float red[4][64];

    float h[INNER];
    const f16* p0 = y0 + (size_t)b*INNER*TT + t;
    const f16* p1 = y1 + (size_t)b*INNER*TT + t;
#pragma unroll
    for (int c = 0; c < INNER; ++c) {
        float v = (float)p0[(size_t)c*TT] + (float)p1[(size_t)c*TT];
        h[c] = v > 0.f ? v : 0.f;
    }
    float part = 0.f;
    int oBase = w*32;
    for (int oi = 0; oi < 32; ++oi) {
        int o = oBase + oi;                      // wave-uniform
        const float* wr = W1 + o*INNER;          // -> s_load
        float z0 = b1[o], z1 = 0.f, z2 = 0.f, z3 = 0.f;
#pragma unroll
        for (int c = 0; c < INNER; c += 4) {
            z0 += wr[c]*h[c];   z1 += wr[c+1]*h[c+1];
            z2 += wr[c+2]*h[c+2]; z3 += wr[c+3]*h[c+3];
        }
        float z = (z0+z1)+(z2+z3);
        z = z > 0.f ? z : 0.f;
        part += W2[o]*z;
    }
    red[w][lane] = part;
    __syncthreads();
    if (w == 0) {
        float acc = b2[0] + red[0][lane] + red[1][lane] + red[2][lane] + red[3][lane];
        out[(size_t)b*TT + t] = acc;
    }
}

extern "C" void kernel_launch(void* const* d_in, const int* in_sizes, int n_in,
                              void* d_out, int out_size, void* d_ws, size_t ws_size,
                              hipStream_t stream) {
    const float* x    = (const float*)d_in[0];
    const float* c    = (const float*)d_in[1];
    const float* fcW  = (const float*)d_in[2];
    const float* fcb  = (const float*)d_in[3];
    const float* inpW = (const float*)d_in[4];
    const float* inpb = (const float*)d_in[5];
    const float* r1W  = (const float*)d_in[6];
    const float* r1b  = (const float*)d_in[7];
    const float* r2W  = (const float*)d_in[8];
    const float* r2b  = (const float*)d_in[9];
    const float* kW   = (const float*)d_in[10];
    const float* kb   = (const float*)d_in[11];
    const float* bW   = (const float*)d_in[12];
    const float* bb   = (const float*)d_in[13];
    const float* l1W  = (const float*)d_in[14];
    const float* l1b  = (const float*)d_in[15];
    const float* l2W  = (const float*)d_in[16];
    const float* l2b  = (const float*)d_in[17];

    float* ws = (float*)d_ws;
    float* h2buf   = ws;                                      // 2*NBL*KH f32
    float* biasbuf = h2buf + (size_t)2*NBL*KH;                // 2*NBL*BCH f32
    float* h1buf   = biasbuf + (size_t)2*NBL*BCH;             // 2*BB*KH*LSEG f32
    f16*   h2h     = (f16*)(h1buf + (size_t)2*BB*KH*LSEG);    // 2*NBL*KH f16
    f16*   bufA    = h2h + (size_t)2*NBL*KH;                  // BB*INNER*TT f16 each
    f16*   bufB    = bufA + (size_t)BB*INNER*TT;
    f16*   bufC    = bufB + (size_t)BB*INNER*TT;
    f16*   kbuf    = bufC + (size_t)BB*INNER*TT;              // 2*LAYERS*NBL*RPL f16

    k_fc<<<BB*TT/256*2, 256, 0, stream>>>(x, fcW, fcb, bufA);

    // predictor chain for BOTH n-blocks, hoisted ahead of the LVC chain
    k_h1<<<32, 256, 0, stream>>>(c, inpW, inpb, h1buf);
    k_h2t<<<4, 256, 0, stream>>>(h1buf, r1W, r1b, r2W, r2b, h2buf, h2h);
    k_biash<<<20, 256, 0, stream>>>(bW, bb, h2buf, biasbuf);
    k_gen<<<2*LAYERS*3*128, 256, 0, stream>>>(kW, kb, h2h, kbuf);

    for (int n = 0; n < 2; ++n) {
        const float* bias_n = biasbuf + (size_t)n*NBL*BCH;
        f16* pin = (n == 0) ? bufA : bufB;
        f16* s0  = (n == 0) ? bufB : bufC;
        f16* s1  = (n == 0) ? bufC : bufA;
        f16* cin = pin;
        for (int i = 0; i < LAYERS; ++i) {
            const f16* kslice = kbuf + (size_t)(n*LAYERS + i)*NBL*RPL;
            f16* cout_ = (i % 2 == 0) ? s0 : s1;
            switch (i) {
                case 0: k_lvc<1> <<<BB*LSEG*4, 256, 0, stream>>>(cin, kslice, bias_n, cout_, i); break;
                case 1: k_lvc<2> <<<BB*LSEG*4, 256, 0, stream>>>(cin, kslice, bias_n, cout_, i); break;
                case 2: k_lvc<4> <<<BB*LSEG*4, 256, 0, stream>>>(cin, kslice, bias_n, cout_, i); break;
                case 3: k_lvc<8> <<<BB*LSEG*4, 256, 0, stream>>>(cin, kslice, bias_n, cout_, i); break;
                case 4: k_lvc<16><<<BB*LSEG*4, 256, 0, stream>>>(cin, kslice, bias_n, cout_, i); break;
            }
            cin = cout_;
        }
    }
    k_head<<<BB*TT/64, 256, 0, stream>>>(bufB, bufC, l1W, l1b, l2W, l2b, (float*)d_out);
}

// Round 4
// 1138.940 us; speedup vs baseline: 1.6637x; 1.0326x over previous
//
#include <hip/hip_runtime.h>
#include <math.h>

// ---------------- problem constants ----------------
#define BB     2
#define LSEG   64
#define HOP    256
#define TT     (LSEG*HOP)      // 16384
#define IN_CH  101
#define INNER  128
#define COND   81
#define LAYERS 5
#define KTAP   3
#define KH     64
#define COUT   256             // 2*INNER
#define RPL    (INNER*COUT*KTAP)   // 98304 rows per layer
#define KCH    (RPL*LAYERS)        // 491520
#define BCH    (COUT*LAYERS)       // 1280
#define NBL    (BB*LSEG)           // 128
#define XS     36                  // padded LDS row stride (f16) - bank stride 18

typedef _Float16 f16;
typedef _Float16 f16x2 __attribute__((ext_vector_type(2)));
typedef _Float16 f16x4 __attribute__((ext_vector_type(4)));
typedef _Float16 f16x8 __attribute__((ext_vector_type(8)));
typedef float    f32x4 __attribute__((ext_vector_type(4)));

// ---------------- fc: h = fc_W @ x + fc_b -> f16 activations ----------------
__global__ __launch_bounds__(256) void k_fc(const float* __restrict__ x,
                                            const float* __restrict__ W,
                                            const float* __restrict__ bias,
                                            f16* __restrict__ out) {
    int half = blockIdx.x & 1;
    int g = (blockIdx.x >> 1)*256 + threadIdx.x;   // over BB*TT
    int b = g / TT, t = g % TT;
    float xv[IN_CH];
    const float* xp = x + (size_t)b*IN_CH*TT + t;
#pragma unroll
    for (int c = 0; c < IN_CH; ++c) xv[c] = xp[(size_t)c*TT];
    f16* op = out + (size_t)b*INNER*TT + t;
    int o0 = half*64;
    for (int o = o0; o < o0 + 64; ++o) {
        const float* wr = W + o*IN_CH;
        float a0 = bias[o], a1 = 0.f, a2 = 0.f, a3 = 0.f;
#pragma unroll
        for (int c = 0; c + 3 < IN_CH; c += 4) {
            a0 += wr[c]*xv[c]; a1 += wr[c+1]*xv[c+1];
            a2 += wr[c+2]*xv[c+2]; a3 += wr[c+3]*xv[c+3];
        }
        a0 += wr[100]*xv[100];
        op[(size_t)o*TT] = (f16)((a0+a1)+(a2+a3));
    }
}

// ---------------- predictor stage 1: h1 = lrelu(conv5(c)), BOTH n-blocks ----
// grid 32 = n(2) x b(2) x og(8)
__global__ __launch_bounds__(256) void k_h1(const float* __restrict__ cc,
                                            const float* __restrict__ iW,
                                            const float* __restrict__ ib,
                                            float* __restrict__ h1buf) {
    int og = blockIdx.x & 7;
    int bp = blockIdx.x >> 3;        // 0..3
    int b  = bp & 1;
    int n  = bp >> 1;
    __shared__ float cL[COND*LSEG];
    __shared__ float wL[8*COND*5];
    int tid = threadIdx.x;
    for (int idx = tid; idx < COND*LSEG; idx += 256)
        cL[idx] = cc[(size_t)b*COND*LSEG + idx];
    const float* wsrc = iW + (size_t)n*KH*COND*5 + (size_t)og*8*COND*5;
    for (int idx = tid; idx < 8*COND*5; idx += 256)
        wL[idx] = wsrc[idx];
    __syncthreads();
#pragma unroll
    for (int rep = 0; rep < 2; ++rep) {
        int idx = rep*256 + tid;
        int ol = idx >> 6, l = idx & 63;
        int o  = og*8 + ol;
        float acc = ib[n*KH + o];
        const float* wrow = wL + ol*COND*5;
        for (int i = 0; i < COND; ++i) {
            const float* crow = cL + i*LSEG;
            const float* w5 = wrow + i*5;
#pragma unroll
            for (int k = 0; k < 5; ++k) {
                int ll = l + k - 2;
                if (ll >= 0 && ll < LSEG) acc += crow[ll]*w5[k];
            }
        }
        h1buf[(((size_t)(n*BB + b))*KH + o)*LSEG + l] = acc >= 0.f ? acc : 0.1f*acc;
    }
}

// ---------------- predictor stage 2: h2, BOTH n-blocks ----------------------
// grid 4 = n(2) x b(2)
__global__ __launch_bounds__(256) void k_h2t(const float* __restrict__ h1buf,
                                             const float* __restrict__ r1W,
                                             const float* __restrict__ r1b,
                                             const float* __restrict__ r2W,
                                             const float* __restrict__ r2b,
                                             float* __restrict__ h2buf,
                                             f16* __restrict__ h2h) {
    int b = blockIdx.x & 1;
    int n = blockIdx.x >> 1;
    __shared__ float h1L[KH*LSEG];
    __shared__ float t1L[KH*LSEG];
    __shared__ float wL[KH*KH];
    int tid = threadIdx.x;
    const float* h1src = h1buf + ((size_t)(n*BB + b))*KH*LSEG;
    for (int idx = tid; idx < KH*LSEG; idx += 256)
        h1L[idx] = h1src[idx];
    for (int idx = tid; idx < KH*KH; idx += 256)
        wL[idx] = r1W[(size_t)n*KH*KH + idx];
    __syncthreads();
#pragma unroll
    for (int rep = 0; rep < 16; ++rep) {
        int idx = rep*256 + tid;
        int o = idx >> 6, l = idx & 63;
        float acc = r1b[n*KH + o];
        const float* wr = wL + o*KH;
#pragma unroll
        for (int i = 0; i < KH; ++i) acc += wr[i]*h1L[i*LSEG + l];
        t1L[idx] = acc >= 0.f ? acc : 0.1f*acc;
    }
    __syncthreads();
    for (int idx = tid; idx < KH*KH; idx += 256)
        wL[idx] = r2W[(size_t)n*KH*KH + idx];
    __syncthreads();
#pragma unroll
    for (int rep = 0; rep < 16; ++rep) {
        int idx = rep*256 + tid;
        int o = idx >> 6, l = idx & 63;
        float acc = r2b[n*KH + o];
        const float* wr = wL + o*KH;
#pragma unroll
        for (int i = 0; i < KH; ++i) acc += wr[i]*t1L[i*LSEG + l];
        float h2 = h1L[o*LSEG + l] + acc;
        size_t row = (size_t)n*NBL + b*LSEG + l;
        h2buf[row*KH + o] = h2;           // [n][bl][o] f32
        h2h  [row*KH + o] = (f16)h2;      // [n][bl][o] f16
    }
}

// ---------------- bias head, BOTH n-blocks ----------------------------------
// grid 20 = 2*BB*BCH/256
__global__ __launch_bounds__(256) void k_biash(const float* __restrict__ bW,
                                               const float* __restrict__ bb,
                                               const float* __restrict__ h2buf,
                                               float* __restrict__ biasbuf) {
    int tg = blockIdx.x*256 + threadIdx.x;       // 0..5119
    int n  = __builtin_amdgcn_readfirstlane(tg / (BB*BCH));
    int rem = tg - n*(BB*BCH);
    int b  = __builtin_amdgcn_readfirstlane(rem / BCH);
    int rb = rem % BCH;
    float w[KH];
    const float4* wp = (const float4*)(bW + ((size_t)n*BCH + rb)*KH);
#pragma unroll
    for (int q = 0; q < KH/4; ++q) {
        float4 v = wp[q];
        w[4*q] = v.x; w[4*q+1] = v.y; w[4*q+2] = v.z; w[4*q+3] = v.w;
    }
    float bv = bb[n*BCH + rb];
    for (int l = 0; l < LSEG; ++l) {
        size_t row = (size_t)n*NBL + b*LSEG + l;
        const float* h2 = h2buf + row*KH;
        float a0 = bv, a1 = 0.f, a2 = 0.f, a3 = 0.f;
#pragma unroll
        for (int j = 0; j < KH; j += 4) {
            a0 += w[j]*h2[j]; a1 += w[j+1]*h2[j+1];
            a2 += w[j+2]*h2[j+2]; a3 += w[j+3]*h2[j+3];
        }
        biasbuf[row*BCH + rb] = (a0+a1)+(a2+a3);
    }
}

// ---------------- kernel generation via MFMA --------------------------------
// GEMM: out[r][bl] = kW[r][:] . h2[bl][:] + kb[r], K=64, computed 16x16x32.
// grid 7680 = n(2) x lay(5) x tap(3) x o(256); 256 thr = 4 waves;
// wave wm owns c in [wm*32, wm*32+32). No LDS, no barriers:
//   A frags: kW row gather (f32->f16 in-register), B frags: h2h direct (L2-hot),
//   C stores: c is contiguous in kbuf -> 8-byte f16x4 packs.
__global__ __launch_bounds__(256) void k_gen(const float* __restrict__ kW,
                                             const float* __restrict__ kb,
                                             const f16*   __restrict__ h2h,
                                             f16*         __restrict__ kbuf) {
    int o   = blockIdx.x & 255;
    int tmp = blockIdx.x >> 8;
    int tap = tmp % 3;  tmp /= 3;
    int lay = tmp % 5;
    int n   = tmp / 5;
    int lane = threadIdx.x & 63;
    int wm   = threadIdx.x >> 6;     // wave's c-group
    int n16  = lane & 15;
    int quad = lane >> 4;

    size_t rbase = (size_t)n*KCH + (size_t)lay*RPL;
    const f16* h2b = h2h + (size_t)n*NBL*KH;

    // A fragments: row = c (lane&15 within 16-tile), k = quad*8 + ks*32 + i
    f16x8 afr[2][2];
#pragma unroll
    for (int j = 0; j < 2; ++j) {
        int c = wm*32 + j*16 + n16;
        const float* arow = kW + (rbase + (size_t)(c*COUT + o)*KTAP + tap)*KH;
#pragma unroll
        for (int ks = 0; ks < 2; ++ks) {
            float4 v0 = *(const float4*)(arow + ks*32 + quad*8);
            float4 v1 = *(const float4*)(arow + ks*32 + quad*8 + 4);
            afr[j][ks] = f16x8{(f16)v0.x,(f16)v0.y,(f16)v0.z,(f16)v0.w,
                               (f16)v1.x,(f16)v1.y,(f16)v1.z,(f16)v1.w};
        }
    }
    // bias into accumulator init: C row = quad*4 + reg
    f32x4 bini[2];
#pragma unroll
    for (int j = 0; j < 2; ++j) {
#pragma unroll
        for (int r = 0; r < 4; ++r) {
            int c = wm*32 + j*16 + quad*4 + r;
            bini[j][r] = kb[rbase + (size_t)(c*COUT + o)*KTAP + tap];
        }
    }
    // gate-interleave: o<128 -> 2o ; o>=128 -> 2(o-128)+1
    int op = (o < 128) ? 2*o : 2*(o-128) + 1;
    size_t obase = (size_t)op*384 + (size_t)tap*128;
    f16* kout = kbuf + ((size_t)(n*LAYERS + lay)*NBL)*RPL + obase;

#pragma unroll 2
    for (int t = 0; t < 8; ++t) {
        int bl = t*16 + n16;                       // B col = C col = lane&15
        const f16* brow = h2b + (size_t)bl*KH;
        f16x8 bf0 = *(const f16x8*)(brow + quad*8);
        f16x8 bf1 = *(const f16x8*)(brow + 32 + quad*8);
        f32x4 acc0 = bini[0], acc1 = bini[1];
        acc0 = __builtin_amdgcn_mfma_f32_16x16x32_f16(afr[0][0], bf0, acc0, 0, 0, 0);
        acc0 = __builtin_amdgcn_mfma_f32_16x16x32_f16(afr[0][1], bf1, acc0, 0, 0, 0);
        acc1 = __builtin_amdgcn_mfma_f32_16x16x32_f16(afr[1][0], bf0, acc1, 0, 0, 0);
        acc1 = __builtin_amdgcn_mfma_f32_16x16x32_f16(afr[1][1], bf1, acc1, 0, 0, 0);
        int c0 = wm*32 + quad*4;
        *(f16x4*)(kout + (size_t)bl*RPL + c0) =
            f16x4{(f16)acc0[0],(f16)acc0[1],(f16)acc0[2],(f16)acc0[3]};
        *(f16x4*)(kout + (size_t)bl*RPL + c0 + 16) =
            f16x4{(f16)acc1[0],(f16)acc1[1],(f16)acc1[2],(f16)acc1[3]};
    }
}

// ---------------- LVC layer via MFMA + fused gating, t-split for occupancy ----
// grid = BB*LSEG*2*4 = 1024; WG (b,l,th,oq) computes C[64 o' x 128 t]
template<int DIL>
__global__ __launch_bounds__(256) void k_lvc(const f16* __restrict__ xin,
                                             const f16* __restrict__ kbuf,
                                             const float* __restrict__ biasbuf,
                                             f16* __restrict__ xout,
                                             int layerIdx) {
    constexpr int WIN = 128 + 2*DIL;
    int wg  = blockIdx.x;
    int o0  = (wg & 3)*64;
    int th  = (wg >> 2) & 1;
    int l   = (wg >> 3) & 63;
    int b   = wg >> 9;
    int bl  = b*LSEG + l;
    int tid = threadIdx.x;
    int w   = tid >> 6;
    int lane = tid & 63;
    int quad = lane >> 4;
    int n16  = lane & 15;
    int wo = (w & 1)*32;
    int wt = (w >> 1)*64;

    __shared__ f16 As[3*64*XS];        // [tap][o'_local][kk 32] padded
    __shared__ f16 xwin[WIN*XS];       // [tw][c] padded (<=160 rows)

    const float* bias_l = biasbuf + (size_t)bl*BCH + layerIdx*COUT;
    f32x4 acc[2][4];
#pragma unroll
    for (int j = 0; j < 2; ++j) {
        int g0 = (o0 + wo + j*16 + quad*4) >> 1;
        f32x4 ini;
        ini[0] = bias_l[g0];       ini[1] = bias_l[g0 + 128];
        ini[2] = bias_l[g0 + 1];   ini[3] = bias_l[g0 + 1 + 128];
#pragma unroll
        for (int tt = 0; tt < 4; ++tt) acc[j][tt] = ini;
    }

    const f16* xb = xin + (size_t)b*INNER*TT;
    const f16* kbl = kbuf + (size_t)bl*RPL + (size_t)o0*384;
    int o_l = tid >> 2, q4 = tid & 3;
    int gt0 = l*256 + th*128 - DIL;

    for (int cb = 0; cb < 4; ++cb) {
        // stage x window (transposed, padded): wave w owns rows c = w, w+4, ...
        for (int cc = w; cc < 32; cc += 4) {
            const f16* src = xb + (size_t)(cb*32 + cc)*TT;
#pragma unroll
            for (int tw0 = 0; tw0 < WIN; tw0 += 64) {
                int tw = tw0 + lane;
                if (tw < WIN) {
                    int gt = gt0 + tw;
                    f16 v = ((unsigned)gt < (unsigned)TT) ? src[gt] : (f16)0.f;
                    xwin[tw*XS + cc] = v;
                }
            }
        }
#pragma unroll
        for (int tap = 0; tap < 3; ++tap) {
            f16x8 v = *(const f16x8*)&kbl[(size_t)o_l*384 + tap*128 + cb*32 + q4*8];
            *(f16x8*)&As[(tap*64 + o_l)*XS + q4*8] = v;
        }
        __syncthreads();
#pragma unroll
        for (int tap = 0; tap < 3; ++tap) {
            f16x8 af0 = *(const f16x8*)&As[(tap*64 + wo + n16)*XS + quad*8];
            f16x8 af1 = *(const f16x8*)&As[(tap*64 + wo + 16 + n16)*XS + quad*8];
#pragma unroll
            for (int tt = 0; tt < 4; ++tt) {
                int trow = wt + tt*16 + n16 + tap*DIL;
                f16x8 bf = *(const f16x8*)&xwin[trow*XS + quad*8];
                acc[0][tt] = __builtin_amdgcn_mfma_f32_16x16x32_f16(af0, bf, acc[0][tt], 0, 0, 0);
                acc[1][tt] = __builtin_amdgcn_mfma_f32_16x16x32_f16(af1, bf, acc[1][tt], 0, 0, 0);
            }
        }
        __syncthreads();
    }
    f16* ob = xout + (size_t)b*INNER*TT + l*256 + th*128;
#pragma unroll
    for (int j = 0; j < 2; ++j) {
        int g0 = (o0 + wo + j*16 + quad*4) >> 1;
#pragma unroll
        for (int tt = 0; tt < 4; ++tt) {
            int tloc = wt + tt*16 + n16;
            f32x4 a = acc[j][tt];
            float s0  = 1.f/(1.f + __expf(-a[0]));
            float th0 = 2.f/(1.f + __expf(-2.f*a[1])) - 1.f;
            float s1  = 1.f/(1.f + __expf(-a[2]));
            float th1 = 2.f/(1.f + __expf(-2.f*a[3])) - 1.f;
            ob[(size_t)g0*TT + tloc]     = (f16)(s0*th0);
            ob[(size_t)(g0+1)*TT + tloc] = (f16)(s1*th1);
        }
    }
}

// ---------------- head: wave-uniform o-ranges -> scalar W1 loads ----------------
__global__ __launch_bounds__(256) void k_head(const f16* __restrict__ y0,
                                              const f16* __restrict__ y1,
                                              const float* __restrict__ W1,
                                              const float* __restrict__ b1,
                                              const float* __restrict__ W2,
                                              const float* __restrict__ b2,
                                              float* __restrict__ out) {
    int b    = blockIdx.x >> 8;
    int tseg = (blockIdx.x & 255)*64;
    int tid  = threadIdx.x;
    int w    = tid >> 6;
    int lane = tid & 63;
    int t    = tseg + lane;
    __shared__ float red[4][64];

    float h[INNER];
    const f16* p0 = y0 + (size_t)b*INNER*TT + t;
    const f16* p1 = y1 + (size_t)b*INNER*TT + t;
#pragma unroll
    for (int c = 0; c < INNER; ++c) {
        float v = (float)p0[(size_t)c*TT] + (float)p1[(size_t)c*TT];
        h[c] = v > 0.f ? v : 0.f;
    }
    float part = 0.f;
    int oBase = w*32;
    for (int oi = 0; oi < 32; ++oi) {
        int o = oBase + oi;                      // wave-uniform
        const float* wr = W1 + o*INNER;          // -> s_load
        float z0 = b1[o], z1 = 0.f, z2 = 0.f, z3 = 0.f;
#pragma unroll
        for (int c = 0; c < INNER; c += 4) {
            z0 += wr[c]*h[c];   z1 += wr[c+1]*h[c+1];
            z2 += wr[c+2]*h[c+2]; z3 += wr[c+3]*h[c+3];
        }
        float z = (z0+z1)+(z2+z3);
        z = z > 0.f ? z : 0.f;
        part += W2[o]*z;
    }
    red[w][lane] = part;
    __syncthreads();
    if (w == 0) {
        float acc = b2[0] + red[0][lane] + red[1][lane] + red[2][lane] + red[3][lane];
        out[(size_t)b*TT + t] = acc;
    }
}

extern "C" void kernel_launch(void* const* d_in, const int* in_sizes, int n_in,
                              void* d_out, int out_size, void* d_ws, size_t ws_size,
                              hipStream_t stream) {
    const float* x    = (const float*)d_in[0];
    const float* c    = (const float*)d_in[1];
    const float* fcW  = (const float*)d_in[2];
    const float* fcb  = (const float*)d_in[3];
    const float* inpW = (const float*)d_in[4];
    const float* inpb = (const float*)d_in[5];
    const float* r1W  = (const float*)d_in[6];
    const float* r1b  = (const float*)d_in[7];
    const float* r2W  = (const float*)d_in[8];
    const float* r2b  = (const float*)d_in[9];
    const float* kW   = (const float*)d_in[10];
    const float* kb   = (const float*)d_in[11];
    const float* bW   = (const float*)d_in[12];
    const float* bb   = (const float*)d_in[13];
    const float* l1W  = (const float*)d_in[14];
    const float* l1b  = (const float*)d_in[15];
    const float* l2W  = (const float*)d_in[16];
    const float* l2b  = (const float*)d_in[17];

    float* ws = (float*)d_ws;
    float* h2buf   = ws;                                      // 2*NBL*KH f32
    float* biasbuf = h2buf + (size_t)2*NBL*KH;                // 2*NBL*BCH f32
    float* h1buf   = biasbuf + (size_t)2*NBL*BCH;             // 2*BB*KH*LSEG f32
    f16*   h2h     = (f16*)(h1buf + (size_t)2*BB*KH*LSEG);    // 2*NBL*KH f16
    f16*   bufA    = h2h + (size_t)2*NBL*KH;                  // BB*INNER*TT f16 each
    f16*   bufB    = bufA + (size_t)BB*INNER*TT;
    f16*   bufC    = bufB + (size_t)BB*INNER*TT;
    f16*   kbuf    = bufC + (size_t)BB*INNER*TT;              // 2*LAYERS*NBL*RPL f16

    k_fc<<<BB*TT/256*2, 256, 0, stream>>>(x, fcW, fcb, bufA);

    // predictor chain for BOTH n-blocks, hoisted ahead of the LVC chain
    k_h1<<<32, 256, 0, stream>>>(c, inpW, inpb, h1buf);
    k_h2t<<<4, 256, 0, stream>>>(h1buf, r1W, r1b, r2W, r2b, h2buf, h2h);
    k_biash<<<20, 256, 0, stream>>>(bW, bb, h2buf, biasbuf);
    k_gen<<<2*LAYERS*3*256, 256, 0, stream>>>(kW, kb, h2h, kbuf);

    for (int n = 0; n < 2; ++n) {
        const float* bias_n = biasbuf + (size_t)n*NBL*BCH;
        f16* pin = (n == 0) ? bufA : bufB;
        f16* s0  = (n == 0) ? bufB : bufC;
        f16* s1  = (n == 0) ? bufC : bufA;
        f16* cin = pin;
        for (int i = 0; i < LAYERS; ++i) {
            const f16* kslice = kbuf + (size_t)(n*LAYERS + i)*NBL*RPL;
            f16* cout_ = (i % 2 == 0) ? s0 : s1;
            switch (i) {
                case 0: k_lvc<1> <<<BB*LSEG*2*4, 256, 0, stream>>>(cin, kslice, bias_n, cout_, i); break;
                case 1: k_lvc<2> <<<BB*LSEG*2*4, 256, 0, stream>>>(cin, kslice, bias_n, cout_, i); break;
                case 2: k_lvc<4> <<<BB*LSEG*2*4, 256, 0, stream>>>(cin, kslice, bias_n, cout_, i); break;
                case 3: k_lvc<8> <<<BB*LSEG*2*4, 256, 0, stream>>>(cin, kslice, bias_n, cout_, i); break;
                case 4: k_lvc<16><<<BB*LSEG*2*4, 256, 0, stream>>>(cin, kslice, bias_n, cout_, i); break;
            }
            cin = cout_;
        }
    }
    k_head<<<BB*TT/64, 256, 0, stream>>>(bufB, bufC, l1W, l1b, l2W, l2b, (float*)d_out);
}

// Round 5
// 1009.241 us; speedup vs baseline: 1.8775x; 1.1285x over previous
//
#include <hip/hip_runtime.h>
#include <math.h>

// ---------------- problem constants ----------------
#define BB     2
#define LSEG   64
#define HOP    256
#define TT     (LSEG*HOP)      // 16384
#define IN_CH  101
#define INNER  128
#define COND   81
#define LAYERS 5
#define KTAP   3
#define KH     64
#define COUT   256             // 2*INNER
#define RPL    (INNER*COUT*KTAP)   // 98304 rows per layer
#define KCH    (RPL*LAYERS)        // 491520
#define BCH    (COUT*LAYERS)       // 1280
#define NBL    (BB*LSEG)           // 128
#define XS     36                  // padded LDS row stride (f16) - bank stride 18
#define AS_STR 72                  // k_gen A-stage stride (f16): 144B, 16B-aligned, 2-way
#define CS_STR 136                 // k_gen C-stage stride (f16): 272B, 16B-aligned, 2-way

typedef _Float16 f16;
typedef _Float16 f16x2 __attribute__((ext_vector_type(2)));
typedef _Float16 f16x4 __attribute__((ext_vector_type(4)));
typedef _Float16 f16x8 __attribute__((ext_vector_type(8)));
typedef float    f32x4 __attribute__((ext_vector_type(4)));

// ---------------- fc: h = fc_W @ x + fc_b -> f16 activations ----------------
__global__ __launch_bounds__(256) void k_fc(const float* __restrict__ x,
                                            const float* __restrict__ W,
                                            const float* __restrict__ bias,
                                            f16* __restrict__ out) {
    int half = blockIdx.x & 1;
    int g = (blockIdx.x >> 1)*256 + threadIdx.x;   // over BB*TT
    int b = g / TT, t = g % TT;
    float xv[IN_CH];
    const float* xp = x + (size_t)b*IN_CH*TT + t;
#pragma unroll
    for (int c = 0; c < IN_CH; ++c) xv[c] = xp[(size_t)c*TT];
    f16* op = out + (size_t)b*INNER*TT + t;
    int o0 = half*64;
    for (int o = o0; o < o0 + 64; ++o) {
        const float* wr = W + o*IN_CH;
        float a0 = bias[o], a1 = 0.f, a2 = 0.f, a3 = 0.f;
#pragma unroll
        for (int c = 0; c + 3 < IN_CH; c += 4) {
            a0 += wr[c]*xv[c]; a1 += wr[c+1]*xv[c+1];
            a2 += wr[c+2]*xv[c+2]; a3 += wr[c+3]*xv[c+3];
        }
        a0 += wr[100]*xv[100];
        op[(size_t)o*TT] = (f16)((a0+a1)+(a2+a3));
    }
}

// ---------------- predictor stage 1: h1 = lrelu(conv5(c)), BOTH n-blocks ----
__global__ __launch_bounds__(256) void k_h1(const float* __restrict__ cc,
                                            const float* __restrict__ iW,
                                            const float* __restrict__ ib,
                                            float* __restrict__ h1buf) {
    int og = blockIdx.x & 7;
    int bp = blockIdx.x >> 3;        // 0..3
    int b  = bp & 1;
    int n  = bp >> 1;
    __shared__ float cL[COND*LSEG];
    __shared__ float wL[8*COND*5];
    int tid = threadIdx.x;
    for (int idx = tid; idx < COND*LSEG; idx += 256)
        cL[idx] = cc[(size_t)b*COND*LSEG + idx];
    const float* wsrc = iW + (size_t)n*KH*COND*5 + (size_t)og*8*COND*5;
    for (int idx = tid; idx < 8*COND*5; idx += 256)
        wL[idx] = wsrc[idx];
    __syncthreads();
#pragma unroll
    for (int rep = 0; rep < 2; ++rep) {
        int idx = rep*256 + tid;
        int ol = idx >> 6, l = idx & 63;
        int o  = og*8 + ol;
        float acc = ib[n*KH + o];
        const float* wrow = wL + ol*COND*5;
        for (int i = 0; i < COND; ++i) {
            const float* crow = cL + i*LSEG;
            const float* w5 = wrow + i*5;
#pragma unroll
            for (int k = 0; k < 5; ++k) {
                int ll = l + k - 2;
                if (ll >= 0 && ll < LSEG) acc += crow[ll]*w5[k];
            }
        }
        h1buf[(((size_t)(n*BB + b))*KH + o)*LSEG + l] = acc >= 0.f ? acc : 0.1f*acc;
    }
}

// ---------------- predictor stage 2: h2, BOTH n-blocks ----------------------
__global__ __launch_bounds__(256) void k_h2t(const float* __restrict__ h1buf,
                                             const float* __restrict__ r1W,
                                             const float* __restrict__ r1b,
                                             const float* __restrict__ r2W,
                                             const float* __restrict__ r2b,
                                             float* __restrict__ h2buf,
                                             f16* __restrict__ h2h) {
    int b = blockIdx.x & 1;
    int n = blockIdx.x >> 1;
    __shared__ float h1L[KH*LSEG];
    __shared__ float t1L[KH*LSEG];
    __shared__ float wL[KH*KH];
    int tid = threadIdx.x;
    const float* h1src = h1buf + ((size_t)(n*BB + b))*KH*LSEG;
    for (int idx = tid; idx < KH*LSEG; idx += 256)
        h1L[idx] = h1src[idx];
    for (int idx = tid; idx < KH*KH; idx += 256)
        wL[idx] = r1W[(size_t)n*KH*KH + idx];
    __syncthreads();
#pragma unroll
    for (int rep = 0; rep < 16; ++rep) {
        int idx = rep*256 + tid;
        int o = idx >> 6, l = idx & 63;
        float acc = r1b[n*KH + o];
        const float* wr = wL + o*KH;
#pragma unroll
        for (int i = 0; i < KH; ++i) acc += wr[i]*h1L[i*LSEG + l];
        t1L[idx] = acc >= 0.f ? acc : 0.1f*acc;
    }
    __syncthreads();
    for (int idx = tid; idx < KH*KH; idx += 256)
        wL[idx] = r2W[(size_t)n*KH*KH + idx];
    __syncthreads();
#pragma unroll
    for (int rep = 0; rep < 16; ++rep) {
        int idx = rep*256 + tid;
        int o = idx >> 6, l = idx & 63;
        float acc = r2b[n*KH + o];
        const float* wr = wL + o*KH;
#pragma unroll
        for (int i = 0; i < KH; ++i) acc += wr[i]*t1L[i*LSEG + l];
        float h2 = h1L[o*LSEG + l] + acc;
        size_t row = (size_t)n*NBL + b*LSEG + l;
        h2buf[row*KH + o] = h2;           // [n][bl][o] f32
        h2h  [row*KH + o] = (f16)h2;      // [n][bl][o] f16
    }
}

// ---------------- bias head, BOTH n-blocks ----------------------------------
__global__ __launch_bounds__(256) void k_biash(const float* __restrict__ bW,
                                               const float* __restrict__ bb,
                                               const float* __restrict__ h2buf,
                                               float* __restrict__ biasbuf) {
    int tg = blockIdx.x*256 + threadIdx.x;       // 0..5119
    int n  = __builtin_amdgcn_readfirstlane(tg / (BB*BCH));
    int rem = tg - n*(BB*BCH);
    int b  = __builtin_amdgcn_readfirstlane(rem / BCH);
    int rb = rem % BCH;
    float w[KH];
    const float4* wp = (const float4*)(bW + ((size_t)n*BCH + rb)*KH);
#pragma unroll
    for (int q = 0; q < KH/4; ++q) {
        float4 v = wp[q];
        w[4*q] = v.x; w[4*q+1] = v.y; w[4*q+2] = v.z; w[4*q+3] = v.w;
    }
    float bv = bb[n*BCH + rb];
    for (int l = 0; l < LSEG; ++l) {
        size_t row = (size_t)n*NBL + b*LSEG + l;
        const float* h2 = h2buf + row*KH;
        float a0 = bv, a1 = 0.f, a2 = 0.f, a3 = 0.f;
#pragma unroll
        for (int j = 0; j < KH; j += 4) {
            a0 += w[j]*h2[j]; a1 += w[j+1]*h2[j+1];
            a2 += w[j+2]*h2[j+2]; a3 += w[j+3]*h2[j+3];
        }
        biasbuf[row*BCH + rb] = (a0+a1)+(a2+a3);
    }
}

// ---------------- kernel generation via MFMA, LDS-staged A and C ------------
// GEMM: out[c][bl] = kW[r(c)][:] . h2[bl][:] + kb, K=64.
// grid 7680 = n(2) x lay(5) x tap(3) x o(256); 256 thr = 4 waves.
// A: coalesced float4 loads (full rows, every line once) -> LDS -> fragments.
// C: fragments -> LDS tile -> coalesced full-line stores (256B per bl-row).
__global__ __launch_bounds__(256) void k_gen(const float* __restrict__ kW,
                                             const float* __restrict__ kb,
                                             const f16*   __restrict__ h2h,
                                             f16*         __restrict__ kbuf) {
    int o   = blockIdx.x & 255;
    int tmp = blockIdx.x >> 8;
    int tap = tmp % 3;  tmp /= 3;
    int lay = tmp % 5;
    int n   = tmp / 5;
    int tid  = threadIdx.x;
    int lane = tid & 63;
    int wm   = tid >> 6;     // wave's c-group
    int n16  = lane & 15;
    int quad = lane >> 4;

    __shared__ f16 smem[128*CS_STR];   // C tile [128 bl][CS_STR]; A aliased [128 c][AS_STR]
    __shared__ float biasL[128];

    size_t rbase = (size_t)n*KCH + (size_t)lay*RPL;
    const f16* h2b = h2h + (size_t)n*NBL*KH;

    // ---- stage A (kW rows, f32->f16) into LDS, fully coalesced ----
#pragma unroll
    for (int it = 0; it < 8; ++it) {
        int g = it*256 + tid;
        int c = g >> 4, f4i = g & 15;
        const float4* arow = (const float4*)(kW + (rbase + (size_t)(c*COUT + o)*KTAP + tap)*KH);
        float4 v = arow[f4i];
        *(f16x4*)&smem[c*AS_STR + f4i*4] = f16x4{(f16)v.x,(f16)v.y,(f16)v.z,(f16)v.w};
    }
    if (tid < 128)
        biasL[tid] = kb[rbase + (size_t)(tid*COUT + o)*KTAP + tap];
    __syncthreads();

    // ---- fragments + bias from LDS ----
    f16x8 afr[2][2];
    f32x4 bini[2];
#pragma unroll
    for (int j = 0; j < 2; ++j) {
        int c = wm*32 + j*16 + n16;
#pragma unroll
        for (int ks = 0; ks < 2; ++ks)
            afr[j][ks] = *(const f16x8*)&smem[c*AS_STR + ks*32 + quad*8];
#pragma unroll
        for (int r = 0; r < 4; ++r)
            bini[j][r] = biasL[wm*32 + j*16 + quad*4 + r];
    }
    __syncthreads();   // everyone done reading A; smem becomes C tile

    // ---- MFMA over 8 bl-tiles, C fragments into LDS ----
#pragma unroll 2
    for (int t = 0; t < 8; ++t) {
        int bl = t*16 + n16;                       // B col = C col
        const f16* brow = h2b + (size_t)bl*KH;
        f16x8 bf0 = *(const f16x8*)(brow + quad*8);
        f16x8 bf1 = *(const f16x8*)(brow + 32 + quad*8);
        f32x4 acc0 = bini[0], acc1 = bini[1];
        acc0 = __builtin_amdgcn_mfma_f32_16x16x32_f16(afr[0][0], bf0, acc0, 0, 0, 0);
        acc0 = __builtin_amdgcn_mfma_f32_16x16x32_f16(afr[0][1], bf1, acc0, 0, 0, 0);
        acc1 = __builtin_amdgcn_mfma_f32_16x16x32_f16(afr[1][0], bf0, acc1, 0, 0, 0);
        acc1 = __builtin_amdgcn_mfma_f32_16x16x32_f16(afr[1][1], bf1, acc1, 0, 0, 0);
        int c0 = wm*32 + quad*4;
        *(f16x4*)&smem[bl*CS_STR + c0] =
            f16x4{(f16)acc0[0],(f16)acc0[1],(f16)acc0[2],(f16)acc0[3]};
        *(f16x4*)&smem[bl*CS_STR + c0 + 16] =
            f16x4{(f16)acc1[0],(f16)acc1[1],(f16)acc1[2],(f16)acc1[3]};
    }
    __syncthreads();

    // ---- coalesced full-line store: 256B contiguous per bl-row ----
    int op = (o < 128) ? 2*o : 2*(o-128) + 1;      // gate-interleave
    f16* kout = kbuf + ((size_t)(n*LAYERS + lay)*NBL)*RPL + (size_t)op*384 + (size_t)tap*128;
#pragma unroll
    for (int it = 0; it < 8; ++it) {
        int g = it*256 + tid;
        int row = g >> 4, seg = g & 15;
        *(f16x8*)(kout + (size_t)row*RPL + seg*8) = *(const f16x8*)&smem[row*CS_STR + seg*8];
    }
}

// ---------------- LVC layer via MFMA + fused gating, 8-wave blocks ----------
// grid = BB*LSEG*4 = 512; 512 thr; WG (b,l,oq) computes C[64 o' x 256 t]
template<int DIL>
__global__ __launch_bounds__(512) void k_lvc(const f16* __restrict__ xin,
                                             const f16* __restrict__ kbuf,
                                             const float* __restrict__ biasbuf,
                                             f16* __restrict__ xout,
                                             int layerIdx) {
    constexpr int WIN = 256 + 2*DIL;
    int wg  = blockIdx.x;
    int o0  = (wg & 3)*64;
    int l   = (wg >> 2) & 63;
    int b   = wg >> 8;
    int bl  = b*LSEG + l;
    int tid = threadIdx.x;
    int w   = tid >> 6;          // 0..7
    int lane = tid & 63;
    int quad = lane >> 4;
    int n16  = lane & 15;
    int wo = (w & 1)*32;
    int wt = (w >> 1)*64;        // t-base: 4 groups x 64

    __shared__ f16 As[3*64*XS];        // [tap][o'_local][kk 32] padded
    __shared__ f16 xwin[288*XS];       // [tw][c] padded

    const float* bias_l = biasbuf + (size_t)bl*BCH + layerIdx*COUT;
    f32x4 acc[2][4];
#pragma unroll
    for (int j = 0; j < 2; ++j) {
        int g0 = (o0 + wo + j*16 + quad*4) >> 1;
        f32x4 ini;
        ini[0] = bias_l[g0];       ini[1] = bias_l[g0 + 128];
        ini[2] = bias_l[g0 + 1];   ini[3] = bias_l[g0 + 1 + 128];
#pragma unroll
        for (int tt = 0; tt < 4; ++tt) acc[j][tt] = ini;
    }

    const f16* xb = xin + (size_t)b*INNER*TT;
    const f16* kbl = kbuf + (size_t)bl*RPL + (size_t)o0*384;
    int o_l = (tid & 255) >> 2, q4 = tid & 3;
    int gt0 = l*256 - DIL;

    for (int cb = 0; cb < 4; ++cb) {
        // stage x window (transposed, padded): wave w owns rows cc = w, w+8, ...
        for (int cc = w; cc < 32; cc += 8) {
            const f16* src = xb + (size_t)(cb*32 + cc)*TT;
#pragma unroll
            for (int tw0 = 0; tw0 < WIN; tw0 += 64) {
                int tw = tw0 + lane;
                if (tw < WIN) {
                    int gt = gt0 + tw;
                    f16 v = ((unsigned)gt < (unsigned)TT) ? src[gt] : (f16)0.f;
                    xwin[tw*XS + cc] = v;
                }
            }
        }
        if (tid < 256) {
#pragma unroll
            for (int tap = 0; tap < 3; ++tap) {
                f16x8 v = *(const f16x8*)&kbl[(size_t)o_l*384 + tap*128 + cb*32 + q4*8];
                *(f16x8*)&As[(tap*64 + o_l)*XS + q4*8] = v;
            }
        }
        __syncthreads();
#pragma unroll
        for (int tap = 0; tap < 3; ++tap) {
            f16x8 af0 = *(const f16x8*)&As[(tap*64 + wo + n16)*XS + quad*8];
            f16x8 af1 = *(const f16x8*)&As[(tap*64 + wo + 16 + n16)*XS + quad*8];
#pragma unroll
            for (int tt = 0; tt < 4; ++tt) {
                int trow = wt + tt*16 + n16 + tap*DIL;
                f16x8 bf = *(const f16x8*)&xwin[trow*XS + quad*8];
                acc[0][tt] = __builtin_amdgcn_mfma_f32_16x16x32_f16(af0, bf, acc[0][tt], 0, 0, 0);
                acc[1][tt] = __builtin_amdgcn_mfma_f32_16x16x32_f16(af1, bf, acc[1][tt], 0, 0, 0);
            }
        }
        __syncthreads();
    }
    f16* ob = xout + (size_t)b*INNER*TT + l*256;
#pragma unroll
    for (int j = 0; j < 2; ++j) {
        int g0 = (o0 + wo + j*16 + quad*4) >> 1;
#pragma unroll
        for (int tt = 0; tt < 4; ++tt) {
            int tloc = wt + tt*16 + n16;
            f32x4 a = acc[j][tt];
            float s0  = 1.f/(1.f + __expf(-a[0]));
            float th0 = 2.f/(1.f + __expf(-2.f*a[1])) - 1.f;
            float s1  = 1.f/(1.f + __expf(-a[2]));
            float th1 = 2.f/(1.f + __expf(-2.f*a[3])) - 1.f;
            ob[(size_t)g0*TT + tloc]     = (f16)(s0*th0);
            ob[(size_t)(g0+1)*TT + tloc] = (f16)(s1*th1);
        }
    }
}

// ---------------- head: wave-uniform o-ranges -> scalar W1 loads ----------------
__global__ __launch_bounds__(256) void k_head(const f16* __restrict__ y0,
                                              const f16* __restrict__ y1,
                                              const float* __restrict__ W1,
                                              const float* __restrict__ b1,
                                              const float* __restrict__ W2,
                                              const float* __restrict__ b2,
                                              float* __restrict__ out) {
    int b    = blockIdx.x >> 8;
    int tseg = (blockIdx.x & 255)*64;
    int tid  = threadIdx.x;
    int w    = tid >> 6;
    int lane = tid & 63;
    int t    = tseg + lane;
    __shared__ float red[4][64];

    float h[INNER];
    const f16* p0 = y0 + (size_t)b*INNER*TT + t;
    const f16* p1 = y1 + (size_t)b*INNER*TT + t;
#pragma unroll
    for (int c = 0; c < INNER; ++c) {
        float v = (float)p0[(size_t)c*TT] + (float)p1[(size_t)c*TT];
        h[c] = v > 0.f ? v : 0.f;
    }
    float part = 0.f;
    int oBase = w*32;
    for (int oi = 0; oi < 32; ++oi) {
        int o = oBase + oi;                      // wave-uniform
        const float* wr = W1 + o*INNER;          // -> s_load
        float z0 = b1[o], z1 = 0.f, z2 = 0.f, z3 = 0.f;
#pragma unroll
        for (int c = 0; c < INNER; c += 4) {
            z0 += wr[c]*h[c];   z1 += wr[c+1]*h[c+1];
            z2 += wr[c+2]*h[c+2]; z3 += wr[c+3]*h[c+3];
        }
        float z = (z0+z1)+(z2+z3);
        z = z > 0.f ? z : 0.f;
        part += W2[o]*z;
    }
    red[w][lane] = part;
    __syncthreads();
    if (w == 0) {
        float acc = b2[0] + red[0][lane] + red[1][lane] + red[2][lane] + red[3][lane];
        out[(size_t)b*TT + t] = acc;
    }
}

extern "C" void kernel_launch(void* const* d_in, const int* in_sizes, int n_in,
                              void* d_out, int out_size, void* d_ws, size_t ws_size,
                              hipStream_t stream) {
    const float* x    = (const float*)d_in[0];
    const float* c    = (const float*)d_in[1];
    const float* fcW  = (const float*)d_in[2];
    const float* fcb  = (const float*)d_in[3];
    const float* inpW = (const float*)d_in[4];
    const float* inpb = (const float*)d_in[5];
    const float* r1W  = (const float*)d_in[6];
    const float* r1b  = (const float*)d_in[7];
    const float* r2W  = (const float*)d_in[8];
    const float* r2b  = (const float*)d_in[9];
    const float* kW   = (const float*)d_in[10];
    const float* kb   = (const float*)d_in[11];
    const float* bW   = (const float*)d_in[12];
    const float* bb   = (const float*)d_in[13];
    const float* l1W  = (const float*)d_in[14];
    const float* l1b  = (const float*)d_in[15];
    const float* l2W  = (const float*)d_in[16];
    const float* l2b  = (const float*)d_in[17];

    float* ws = (float*)d_ws;
    float* h2buf   = ws;                                      // 2*NBL*KH f32
    float* biasbuf = h2buf + (size_t)2*NBL*KH;                // 2*NBL*BCH f32
    float* h1buf   = biasbuf + (size_t)2*NBL*BCH;             // 2*BB*KH*LSEG f32
    f16*   h2h     = (f16*)(h1buf + (size_t)2*BB*KH*LSEG);    // 2*NBL*KH f16
    f16*   bufA    = h2h + (size_t)2*NBL*KH;                  // BB*INNER*TT f16 each
    f16*   bufB    = bufA + (size_t)BB*INNER*TT;
    f16*   bufC    = bufB + (size_t)BB*INNER*TT;
    f16*   kbuf    = bufC + (size_t)BB*INNER*TT;              // 2*LAYERS*NBL*RPL f16

    k_fc<<<BB*TT/256*2, 256, 0, stream>>>(x, fcW, fcb, bufA);

    // predictor chain for BOTH n-blocks, hoisted ahead of the LVC chain
    k_h1<<<32, 256, 0, stream>>>(c, inpW, inpb, h1buf);
    k_h2t<<<4, 256, 0, stream>>>(h1buf, r1W, r1b, r2W, r2b, h2buf, h2h);
    k_biash<<<20, 256, 0, stream>>>(bW, bb, h2buf, biasbuf);
    k_gen<<<2*LAYERS*3*256, 256, 0, stream>>>(kW, kb, h2h, kbuf);

    for (int n = 0; n < 2; ++n) {
        const float* bias_n = biasbuf + (size_t)n*NBL*BCH;
        f16* pin = (n == 0) ? bufA : bufB;
        f16* s0  = (n == 0) ? bufB : bufC;
        f16* s1  = (n == 0) ? bufC : bufA;
        f16* cin = pin;
        for (int i = 0; i < LAYERS; ++i) {
            const f16* kslice = kbuf + (size_t)(n*LAYERS + i)*NBL*RPL;
            f16* cout_ = (i % 2 == 0) ? s0 : s1;
            switch (i) {
                case 0: k_lvc<1> <<<BB*LSEG*4, 512, 0, stream>>>(cin, kslice, bias_n, cout_, i); break;
                case 1: k_lvc<2> <<<BB*LSEG*4, 512, 0, stream>>>(cin, kslice, bias_n, cout_, i); break;
                case 2: k_lvc<4> <<<BB*LSEG*4, 512, 0, stream>>>(cin, kslice, bias_n, cout_, i); break;
                case 3: k_lvc<8> <<<BB*LSEG*4, 512, 0, stream>>>(cin, kslice, bias_n, cout_, i); break;
                case 4: k_lvc<16><<<BB*LSEG*4, 512, 0, stream>>>(cin, kslice, bias_n, cout_, i); break;
            }
            cin = cout_;
        }
    }
    k_head<<<BB*TT/64, 256, 0, stream>>>(bufB, bufC, l1W, l1b, l2W, l2b, (float*)d_out);
}